// Round 1
// baseline (4135.381 us; speedup 1.0000x reference)
//
#include <hip/hip_runtime.h>

#define NUSERS 50000
#define NITEMS 20000
#define NEDGES 400000

// ---------- helpers ----------
__device__ __forceinline__ unsigned ford(float f) {
  unsigned b = __float_as_uint(f);
  return (b & 0x80000000u) ? ~b : (b | 0x80000000u);   // monotone float->uint
}
__device__ __forceinline__ float fdec(unsigned u) {
  return __uint_as_float((u & 0x80000000u) ? (u & 0x7FFFFFFFu) : ~u);
}

// ---------- fold: Wr[h*K+f] = sum_d W[f, h*dh+d] * A[1,h,d] ----------
__global__ void fold_k(const float* __restrict__ W, const float* __restrict__ A,
                       float* __restrict__ fold, int K, int H, int dh) {
  int t = blockIdx.x * blockDim.x + threadIdx.x;
  if (t >= K * H) return;
  int h = t / K, f = t - h * K;
  int HD = H * dh;
  const float* A1 = A + HD;
  float s = 0.f;
  for (int d = 0; d < dh; ++d) s += W[f * HD + h * dh + d] * A1[h * dh + d];
  fold[h * K + f] = s;
}

// ---------- fp32 GEMM: C[M,N] = A[M,K] @ B[K,N]; N%64==0, K%16==0 ----------
__global__ __launch_bounds__(256) void sgemm_k(const float* __restrict__ A,
                                               const float* __restrict__ B,
                                               float* __restrict__ C,
                                               int M, int N, int K) {
  __shared__ float As[16][64];  // [k][m]
  __shared__ float Bs[16][64];  // [k][n]
  int tid = threadIdx.x;
  int bx = blockIdx.x, by = blockIdx.y;
  int tx = tid & 15, ty = tid >> 4;
  int row0 = by * 64, col0 = bx * 64;
  float acc[4][4] = {};
  for (int k0 = 0; k0 < K; k0 += 16) {
#pragma unroll
    for (int s = 0; s < 4; ++s) {
      int idx = tid + s * 256;          // 0..1023
      int m = idx >> 4, kk = idx & 15;  // A tile
      int r = row0 + m;
      As[kk][m] = (r < M) ? A[(long)r * K + k0 + kk] : 0.0f;
      int k2 = idx >> 6, n2 = idx & 63; // B tile
      Bs[k2][n2] = B[(long)(k0 + k2) * N + col0 + n2];
    }
    __syncthreads();
#pragma unroll
    for (int kk = 0; kk < 16; ++kk) {
      float4 av = *reinterpret_cast<const float4*>(&As[kk][ty << 2]);
      float4 bv = *reinterpret_cast<const float4*>(&Bs[kk][tx << 2]);
      float a[4] = {av.x, av.y, av.z, av.w};
      float b[4] = {bv.x, bv.y, bv.z, bv.w};
#pragma unroll
      for (int i = 0; i < 4; ++i)
#pragma unroll
        for (int j = 0; j < 4; ++j) acc[i][j] += a[i] * b[j];
    }
    __syncthreads();
  }
#pragma unroll
  for (int i = 0; i < 4; ++i) {
    int r = row0 + (ty << 2) + i;
    if (r < M) {
      float4 v = make_float4(acc[i][0], acc[i][1], acc[i][2], acc[i][3]);
      *reinterpret_cast<float4*>(&C[(long)r * N + col0 + (tx << 2)]) = v;
    }
  }
}

// ---------- er: er[n,h] = x[n,:] @ fold[h,:]  (H=4, block=256) ----------
__global__ __launch_bounds__(256) void er_k(const float* __restrict__ X,
                                            const float* __restrict__ fold,
                                            float* __restrict__ er, int K) {
  __shared__ float xs[256];
  int n = blockIdx.x, t = threadIdx.x;
  if (t < K) xs[t] = X[(long)n * K + t];
  __syncthreads();
  int h = t >> 6, l = t & 63;
  float p = 0.f;
  for (int f = l; f < K; f += 64) p += xs[f] * fold[h * K + f];
#pragma unroll
  for (int off = 32; off; off >>= 1) p += __shfl_down(p, off, 64);
  if (l == 0) er[n * 4 + h] = p;
}

// ---------- el: el[n,h] = hs[n,h,:] . A0[h,:]  (block = H*dh) ----------
__global__ void el_k(const float* __restrict__ hs, const float* __restrict__ A0,
                     float* __restrict__ el, int H, int dh) {
  int n = blockIdx.x, t = threadIdx.x;
  int W = blockDim.x;
  float v = hs[(long)n * W + t] * A0[t];
  for (int off = dh >> 1; off; off >>= 1) v += __shfl_down(v, off, dh);
  if ((t & (dh - 1)) == 0) el[n * H + t / dh] = v;
}

// ---------- edge pass 1: logits + segment max ----------
__global__ void edge1_k(const float* __restrict__ el, const float* __restrict__ er,
                        const int* __restrict__ src, const int* __restrict__ dst,
                        float* __restrict__ ebuf, unsigned* __restrict__ mbuf) {
  int idx = blockIdx.x * blockDim.x + threadIdx.x;
  if (idx >= NEDGES * 4) return;
  int e = idx >> 2, h = idx & 3;
  float v = el[src[e] * 4 + h] + er[dst[e] * 4 + h];
  v = (v > 0.f) ? v : 0.2f * v;              // attn leaky_relu, slope 0.2
  ebuf[idx] = v;
  atomicMax(&mbuf[dst[e] * 4 + h], ford(v));
}

// ---------- edge pass 2: exp + segment sum ----------
__global__ void edge2_k(float* __restrict__ ebuf, const unsigned* __restrict__ mbuf,
                        float* __restrict__ sbuf, const int* __restrict__ dst) {
  int idx = blockIdx.x * blockDim.x + threadIdx.x;
  if (idx >= NEDGES * 4) return;
  int e = idx >> 2, h = idx & 3;
  int d = dst[e];
  float ee = expf(ebuf[idx] - fdec(mbuf[d * 4 + h]));
  ebuf[idx] = ee;
  atomicAdd(&sbuf[d * 4 + h], ee);
}

// ---------- edge pass 2b: normalize -> alpha ----------
__global__ void edge2b_k(float* __restrict__ ebuf, const float* __restrict__ sbuf,
                         const int* __restrict__ dst) {
  int idx = blockIdx.x * blockDim.x + threadIdx.x;
  if (idx >= NEDGES * 4) return;
  int e = idx >> 2, h = idx & 3;
  ebuf[idx] = ebuf[idx] / sbuf[dst[e] * 4 + h];
}

// ---------- edge pass 3: aggregate (block per edge, W lanes) ----------
__global__ void edge3_k(const float* __restrict__ alpha, const float* __restrict__ hs,
                        const int* __restrict__ src, const int* __restrict__ dst,
                        float* __restrict__ agg, int W, int dh) {
  int e = blockIdx.x;
  int c = threadIdx.x;
  int s = src[e], d = dst[e];
  int h = c / dh;
  float a = alpha[e * 4 + h];
  atomicAdd(&agg[(long)d * W + c], a * hs[(long)s * W + c]);
}

// ---------- BN stats: column sum / sumsq (C=256) ----------
__global__ __launch_bounds__(256) void bn_stats_k(const float* __restrict__ x,
                                                  float* __restrict__ sums, int N) {
  const int C = 256;
  int c = threadIdx.x;
  int r0 = blockIdx.x * 64;
  int r1 = min(r0 + 64, N);
  float s = 0.f, s2 = 0.f;
  for (int r = r0; r < r1; ++r) {
    float v = x[(long)r * C + c];
    s += v; s2 += v * v;
  }
  atomicAdd(&sums[c], s);
  atomicAdd(&sums[C + c], s2);
}

// ---------- BN apply + activation (in place) ----------
__global__ void bn_apply_k(float* __restrict__ x, const float* __restrict__ sums,
                           const float* __restrict__ gb, int N, int act) {
  const int C = 256;
  int idx = blockIdx.x * blockDim.x + threadIdx.x;
  if (idx >= N * C) return;
  int c = idx & 255;
  float inv_n = 1.0f / (float)N;
  float mean = sums[c] * inv_n;
  float var = sums[C + c] * inv_n - mean * mean;
  float v = gb[c] * (x[idx] - mean) * rsqrtf(var + 1e-5f) + gb[C + c];
  v = act ? tanhf(v) : (v > 0.f ? v : 0.01f * v);
  x[idx] = v;
}

extern "C" void kernel_launch(void* const* d_in, const int* in_sizes, int n_in,
                              void* d_out, int out_size, void* d_ws, size_t ws_size,
                              hipStream_t stream) {
  const float* x_user = (const float*)d_in[0];
  const float* x_item = (const float*)d_in[1];
  const int* eu = (const int*)d_in[2];
  const int* ei = (const int*)d_in[3];
  const float *Wm[4][2], *Am[4][2];
  for (int L = 0; L < 4; ++L) {
    Wm[L][0] = (const float*)d_in[4 + L * 4 + 0];
    Am[L][0] = (const float*)d_in[4 + L * 4 + 1];
    Wm[L][1] = (const float*)d_in[4 + L * 4 + 2];
    Am[L][1] = (const float*)d_in[4 + L * 4 + 3];
  }
  const float* bnu = (const float*)d_in[20];
  const float* bni = (const float*)d_in[21];
  float* out = (float*)d_out;

  float* ws = (float*)d_ws;
  size_t o = 0;
  float* h_u = ws + o;  o += (size_t)NUSERS * 256;
  float* h_i = ws + o;  o += (size_t)NITEMS * 256;
  float* hs_u = ws + o; o += (size_t)NUSERS * 256;
  float* hs_i = ws + o; o += (size_t)NITEMS * 256;
  float* el_u = ws + o; o += (size_t)NUSERS * 4;
  float* er_u = ws + o; o += (size_t)NUSERS * 4;
  float* s_u = ws + o;  o += (size_t)NUSERS * 4;
  unsigned* m_u = (unsigned*)(ws + o); o += (size_t)NUSERS * 4;
  float* el_i = ws + o; o += (size_t)NITEMS * 4;
  float* er_i = ws + o; o += (size_t)NITEMS * 4;
  float* s_i = ws + o;  o += (size_t)NITEMS * 4;
  unsigned* m_i = (unsigned*)(ws + o); o += (size_t)NITEMS * 4;
  float* ebuf = ws + o; o += (size_t)NEDGES * 4;
  float* fold_ui = ws + o; o += 1024;
  float* fold_iu = ws + o; o += 1024;
  float* bns_u = ws + o; o += 512;
  float* bns_i = ws + o; o += 512;

  const float* in_u = x_user;
  const float* in_i = x_item;
  int K = 128;
  const int g_eh = (NEDGES * 4 + 255) / 256;

  for (int L = 0; L < 4; ++L) {
    const int H = 4;
    const int dh = (L == 3) ? 32 : 64;
    const int W = H * dh;
    const float* W_ui = Wm[L][0]; const float* A_ui = Am[L][0];
    const float* W_iu = Wm[L][1]; const float* A_iu = Am[L][1];

    // folded dst-side projections
    fold_k<<<dim3((K * H + 255) / 256), dim3(256), 0, stream>>>(W_ui, A_ui, fold_ui, K, H, dh);
    fold_k<<<dim3((K * H + 255) / 256), dim3(256), 0, stream>>>(W_iu, A_iu, fold_iu, K, H, dh);

    // src projections
    sgemm_k<<<dim3(W / 64, (NUSERS + 63) / 64), dim3(256), 0, stream>>>(in_u, W_ui, hs_u, NUSERS, W, K);
    sgemm_k<<<dim3(W / 64, (NITEMS + 63) / 64), dim3(256), 0, stream>>>(in_i, W_iu, hs_i, NITEMS, W, K);

    // er (dst side), el (src side)
    er_k<<<dim3(NITEMS), dim3(256), 0, stream>>>(in_i, fold_ui, er_i, K);
    er_k<<<dim3(NUSERS), dim3(256), 0, stream>>>(in_u, fold_iu, er_u, K);
    el_k<<<dim3(NUSERS), dim3(W), 0, stream>>>(hs_u, A_ui, el_u, H, dh);
    el_k<<<dim3(NITEMS), dim3(W), 0, stream>>>(hs_i, A_iu, el_i, H, dh);

    // zero softmax state (ordered-uint max identity == 0)
    hipMemsetAsync(m_u, 0, (size_t)NUSERS * 4 * sizeof(float), stream);
    hipMemsetAsync(s_u, 0, (size_t)NUSERS * 4 * sizeof(float), stream);
    hipMemsetAsync(m_i, 0, (size_t)NITEMS * 4 * sizeof(float), stream);
    hipMemsetAsync(s_i, 0, (size_t)NITEMS * 4 * sizeof(float), stream);

    // aggregation targets (inputs are dead past this point; safe to reuse h_*)
    float* agg_u; float* agg_i;
    if (L < 3) {
      agg_u = h_u; agg_i = h_i;
      hipMemsetAsync(h_u, 0, (size_t)NUSERS * 256 * sizeof(float), stream);
      hipMemsetAsync(h_i, 0, (size_t)NITEMS * 256 * sizeof(float), stream);
    } else {
      agg_u = out; agg_i = out + (size_t)NUSERS * 128;
      hipMemsetAsync(out, 0, (size_t)(NUSERS + NITEMS) * 128 * sizeof(float), stream);
    }

    // relation ui: src=user -> dst=item
    edge1_k<<<dim3(g_eh), dim3(256), 0, stream>>>(el_u, er_i, eu, ei, ebuf, m_i);
    edge2_k<<<dim3(g_eh), dim3(256), 0, stream>>>(ebuf, m_i, s_i, ei);
    edge2b_k<<<dim3(g_eh), dim3(256), 0, stream>>>(ebuf, s_i, ei);
    edge3_k<<<dim3(NEDGES), dim3(W), 0, stream>>>(ebuf, hs_u, eu, ei, agg_i, W, dh);

    // relation iu: src=item -> dst=user
    edge1_k<<<dim3(g_eh), dim3(256), 0, stream>>>(el_i, er_u, ei, eu, ebuf, m_u);
    edge2_k<<<dim3(g_eh), dim3(256), 0, stream>>>(ebuf, m_u, s_u, eu);
    edge2b_k<<<dim3(g_eh), dim3(256), 0, stream>>>(ebuf, s_u, eu);
    edge3_k<<<dim3(NEDGES), dim3(W), 0, stream>>>(ebuf, hs_i, ei, eu, agg_u, W, dh);

    if (L < 3) {
      hipMemsetAsync(bns_u, 0, 512 * sizeof(float), stream);
      hipMemsetAsync(bns_i, 0, 512 * sizeof(float), stream);
      bn_stats_k<<<dim3((NUSERS + 63) / 64), dim3(256), 0, stream>>>(agg_u, bns_u, NUSERS);
      bn_stats_k<<<dim3((NITEMS + 63) / 64), dim3(256), 0, stream>>>(agg_i, bns_i, NITEMS);
      bn_apply_k<<<dim3((NUSERS * 256 + 255) / 256), dim3(256), 0, stream>>>(agg_u, bns_u, bnu + L * 512, NUSERS, L == 2);
      bn_apply_k<<<dim3((NITEMS * 256 + 255) / 256), dim3(256), 0, stream>>>(agg_i, bns_i, bni + L * 512, NITEMS, L == 2);
      in_u = h_u; in_i = h_i; K = 256;
    }
  }
}

// Round 2
// 2592.894 us; speedup vs baseline: 1.5949x; 1.5949x over previous
//
#include <hip/hip_runtime.h>

#define NUSERS 50000
#define NITEMS 20000
#define NEDGES 400000

// ---------- helpers ----------
__device__ __forceinline__ unsigned ford(float f) {
  unsigned b = __float_as_uint(f);
  return (b & 0x80000000u) ? ~b : (b | 0x80000000u);   // monotone float->uint
}
__device__ __forceinline__ float fdec(unsigned u) {
  return __uint_as_float((u & 0x80000000u) ? (u & 0x7FFFFFFFu) : ~u);
}

// ---------- fold: Wr[h*K+f] = sum_d W[f, h*dh+d] * A[1,h,d] ----------
__global__ void fold_k(const float* __restrict__ W, const float* __restrict__ A,
                       float* __restrict__ fold, int K, int H, int dh) {
  int t = blockIdx.x * blockDim.x + threadIdx.x;
  if (t >= K * H) return;
  int h = t / K, f = t - h * K;
  int HD = H * dh;
  const float* A1 = A + HD;
  float s = 0.f;
  for (int d = 0; d < dh; ++d) s += W[f * HD + h * dh + d] * A1[h * dh + d];
  fold[h * K + f] = s;
}

// ---------- fp32 GEMM: C[M,N] = A[M,K] @ B[K,N]; N%64==0, K%16==0 ----------
__global__ __launch_bounds__(256) void sgemm_k(const float* __restrict__ A,
                                               const float* __restrict__ B,
                                               float* __restrict__ C,
                                               int M, int N, int K) {
  __shared__ float As[16][64];  // [k][m]
  __shared__ float Bs[16][64];  // [k][n]
  int tid = threadIdx.x;
  int bx = blockIdx.x, by = blockIdx.y;
  int tx = tid & 15, ty = tid >> 4;
  int row0 = by * 64, col0 = bx * 64;
  float acc[4][4] = {};
  for (int k0 = 0; k0 < K; k0 += 16) {
#pragma unroll
    for (int s = 0; s < 4; ++s) {
      int idx = tid + s * 256;          // 0..1023
      int m = idx >> 4, kk = idx & 15;  // A tile
      int r = row0 + m;
      As[kk][m] = (r < M) ? A[(long)r * K + k0 + kk] : 0.0f;
      int k2 = idx >> 6, n2 = idx & 63; // B tile
      Bs[k2][n2] = B[(long)(k0 + k2) * N + col0 + n2];
    }
    __syncthreads();
#pragma unroll
    for (int kk = 0; kk < 16; ++kk) {
      float4 av = *reinterpret_cast<const float4*>(&As[kk][ty << 2]);
      float4 bv = *reinterpret_cast<const float4*>(&Bs[kk][tx << 2]);
      float a[4] = {av.x, av.y, av.z, av.w};
      float b[4] = {bv.x, bv.y, bv.z, bv.w};
#pragma unroll
      for (int i = 0; i < 4; ++i)
#pragma unroll
        for (int j = 0; j < 4; ++j) acc[i][j] += a[i] * b[j];
    }
    __syncthreads();
  }
#pragma unroll
  for (int i = 0; i < 4; ++i) {
    int r = row0 + (ty << 2) + i;
    if (r < M) {
      float4 v = make_float4(acc[i][0], acc[i][1], acc[i][2], acc[i][3]);
      *reinterpret_cast<float4*>(&C[(long)r * N + col0 + (tx << 2)]) = v;
    }
  }
}

// ---------- er: er[n,h] = x[n,:] @ fold[h,:]  (H=4, block=256) ----------
__global__ __launch_bounds__(256) void er_k(const float* __restrict__ X,
                                            const float* __restrict__ fold,
                                            float* __restrict__ er, int K) {
  __shared__ float xs[256];
  int n = blockIdx.x, t = threadIdx.x;
  if (t < K) xs[t] = X[(long)n * K + t];
  __syncthreads();
  int h = t >> 6, l = t & 63;
  float p = 0.f;
  for (int f = l; f < K; f += 64) p += xs[f] * fold[h * K + f];
#pragma unroll
  for (int off = 32; off; off >>= 1) p += __shfl_down(p, off, 64);
  if (l == 0) er[n * 4 + h] = p;
}

// ---------- el: el[n,h] = hs[n,h,:] . A0[h,:]  (block = H*dh) ----------
__global__ void el_k(const float* __restrict__ hs, const float* __restrict__ A0,
                     float* __restrict__ el, int H, int dh) {
  int n = blockIdx.x, t = threadIdx.x;
  int W = blockDim.x;
  float v = hs[(long)n * W + t] * A0[t];
  for (int off = dh >> 1; off; off >>= 1) v += __shfl_down(v, off, dh);
  if ((t & (dh - 1)) == 0) el[n * H + t / dh] = v;
}

// ---------- edge pass 1: logits + segment max ----------
__global__ void edge1_k(const float* __restrict__ el, const float* __restrict__ er,
                        const int* __restrict__ src, const int* __restrict__ dst,
                        float* __restrict__ ebuf, unsigned* __restrict__ mbuf) {
  int idx = blockIdx.x * blockDim.x + threadIdx.x;
  if (idx >= NEDGES * 4) return;
  int e = idx >> 2, h = idx & 3;
  float v = el[src[e] * 4 + h] + er[dst[e] * 4 + h];
  v = (v > 0.f) ? v : 0.2f * v;              // attn leaky_relu, slope 0.2
  ebuf[idx] = v;
  atomicMax(&mbuf[dst[e] * 4 + h], ford(v));
}

// ---------- edge pass 2: exp + segment sum ----------
__global__ void edge2_k(float* __restrict__ ebuf, const unsigned* __restrict__ mbuf,
                        float* __restrict__ sbuf, const int* __restrict__ dst) {
  int idx = blockIdx.x * blockDim.x + threadIdx.x;
  if (idx >= NEDGES * 4) return;
  int e = idx >> 2, h = idx & 3;
  int d = dst[e];
  float ee = expf(ebuf[idx] - fdec(mbuf[d * 4 + h]));
  ebuf[idx] = ee;
  atomicAdd(&sbuf[d * 4 + h], ee);
}

// ---------- CSR build ----------
__global__ void hist_k(const int* __restrict__ dst, int* __restrict__ deg) {
  int e = blockIdx.x * blockDim.x + threadIdx.x;
  if (e < NEDGES) atomicAdd(&deg[dst[e]], 1);
}

// chunk = 1024 elems / block (256 thr x 4)
__global__ __launch_bounds__(256) void scan1_k(const int* __restrict__ deg,
                                               int* __restrict__ bsum, int N) {
  __shared__ int red[256];
  int base = blockIdx.x * 1024, t = threadIdx.x;
  int s = 0;
#pragma unroll
  for (int j = 0; j < 4; ++j) { int i = base + t * 4 + j; s += (i < N) ? deg[i] : 0; }
  red[t] = s; __syncthreads();
  for (int off = 128; off; off >>= 1) { if (t < off) red[t] += red[t + off]; __syncthreads(); }
  if (t == 0) bsum[blockIdx.x] = red[0];
}

__global__ void scan2_k(int* __restrict__ bsum, int nb) {
  if (threadIdx.x == 0) {
    int run = 0;
    for (int i = 0; i < nb; ++i) { int v = bsum[i]; bsum[i] = run; run += v; }
  }
}

__global__ __launch_bounds__(256) void scan3_k(const int* __restrict__ deg,
                                               const int* __restrict__ bsum,
                                               int* __restrict__ rowptr, int N) {
  __shared__ int tsum[256];
  int base = blockIdx.x * 1024, t = threadIdx.x;
  int v[4]; int s = 0;
#pragma unroll
  for (int j = 0; j < 4; ++j) { int i = base + t * 4 + j; v[j] = (i < N) ? deg[i] : 0; s += v[j]; }
  tsum[t] = s; __syncthreads();
  for (int off = 1; off < 256; off <<= 1) {
    int x = (t >= off) ? tsum[t - off] : 0;
    __syncthreads();
    tsum[t] += x;
    __syncthreads();
  }
  int run = bsum[blockIdx.x] + ((t > 0) ? tsum[t - 1] : 0);
#pragma unroll
  for (int j = 0; j < 4; ++j) {
    int i = base + t * 4 + j;
    if (i < N) rowptr[i] = run;
    run += v[j];
  }
}

__global__ void setval_k(int* __restrict__ p, int v) { *p = v; }

__global__ void copy_int_k(const int* __restrict__ a, int* __restrict__ b, int N) {
  int i = blockIdx.x * blockDim.x + threadIdx.x;
  if (i < N) b[i] = a[i];
}

__global__ void scat_k(const int* __restrict__ dst, const int* __restrict__ src,
                       int* __restrict__ cursor, int* __restrict__ csr_src,
                       int* __restrict__ csr_eid) {
  int e = blockIdx.x * blockDim.x + threadIdx.x;
  if (e >= NEDGES) return;
  int d = dst[e];
  int p = atomicAdd(&cursor[d], 1);
  csr_src[p] = src[e];
  csr_eid[p] = e;
}

// ---------- fused normalize + CSR gather aggregate ----------
// block = W threads, one block per dst node. out[d,c] = sum_e alpha * hs[src,c]
__global__ void gather_k(const float* __restrict__ ebuf, const float* __restrict__ sbuf,
                         const int* __restrict__ rowptr, const int* __restrict__ csr_src,
                         const int* __restrict__ csr_eid, const float* __restrict__ hs,
                         float* __restrict__ outbuf, int W, int dh) {
  int d = blockIdx.x;
  int c = threadIdx.x;
  int h = c / dh;
  int s0 = rowptr[d], s1 = rowptr[d + 1];
  float acc = 0.f;
  for (int k = s0; k < s1; ++k) {
    int s = csr_src[k];
    int e = csr_eid[k];
    acc += ebuf[e * 4 + h] * hs[(long)s * W + c];
  }
  float inv = (s1 > s0) ? 1.0f / sbuf[d * 4 + h] : 0.0f;
  outbuf[(long)d * W + c] = acc * inv;
}

// ---------- BN stats: column sum / sumsq (C=256) ----------
__global__ __launch_bounds__(256) void bn_stats_k(const float* __restrict__ x,
                                                  float* __restrict__ sums, int N) {
  const int C = 256;
  int c = threadIdx.x;
  int r0 = blockIdx.x * 64;
  int r1 = min(r0 + 64, N);
  float s = 0.f, s2 = 0.f;
  for (int r = r0; r < r1; ++r) {
    float v = x[(long)r * C + c];
    s += v; s2 += v * v;
  }
  atomicAdd(&sums[c], s);
  atomicAdd(&sums[C + c], s2);
}

// ---------- BN apply + activation (in place) ----------
__global__ void bn_apply_k(float* __restrict__ x, const float* __restrict__ sums,
                           const float* __restrict__ gb, int N, int act) {
  const int C = 256;
  int idx = blockIdx.x * blockDim.x + threadIdx.x;
  if (idx >= N * C) return;
  int c = idx & 255;
  float inv_n = 1.0f / (float)N;
  float mean = sums[c] * inv_n;
  float var = sums[C + c] * inv_n - mean * mean;
  float v = gb[c] * (x[idx] - mean) * rsqrtf(var + 1e-5f) + gb[C + c];
  v = act ? tanhf(v) : (v > 0.f ? v : 0.01f * v);
  x[idx] = v;
}

extern "C" void kernel_launch(void* const* d_in, const int* in_sizes, int n_in,
                              void* d_out, int out_size, void* d_ws, size_t ws_size,
                              hipStream_t stream) {
  const float* x_user = (const float*)d_in[0];
  const float* x_item = (const float*)d_in[1];
  const int* eu = (const int*)d_in[2];
  const int* ei = (const int*)d_in[3];
  const float *Wm[4][2], *Am[4][2];
  for (int L = 0; L < 4; ++L) {
    Wm[L][0] = (const float*)d_in[4 + L * 4 + 0];
    Am[L][0] = (const float*)d_in[4 + L * 4 + 1];
    Wm[L][1] = (const float*)d_in[4 + L * 4 + 2];
    Am[L][1] = (const float*)d_in[4 + L * 4 + 3];
  }
  const float* bnu = (const float*)d_in[20];
  const float* bni = (const float*)d_in[21];
  float* out = (float*)d_out;

  float* ws = (float*)d_ws;
  size_t o = 0;
  float* h_u = ws + o;  o += (size_t)NUSERS * 256;
  float* h_i = ws + o;  o += (size_t)NITEMS * 256;
  float* hs_u = ws + o; o += (size_t)NUSERS * 256;
  float* hs_i = ws + o; o += (size_t)NITEMS * 256;
  float* el_u = ws + o; o += (size_t)NUSERS * 4;
  float* er_u = ws + o; o += (size_t)NUSERS * 4;
  float* s_u = ws + o;  o += (size_t)NUSERS * 4;
  unsigned* m_u = (unsigned*)(ws + o); o += (size_t)NUSERS * 4;
  float* el_i = ws + o; o += (size_t)NITEMS * 4;
  float* er_i = ws + o; o += (size_t)NITEMS * 4;
  float* s_i = ws + o;  o += (size_t)NITEMS * 4;
  unsigned* m_i = (unsigned*)(ws + o); o += (size_t)NITEMS * 4;
  float* ebuf = ws + o; o += (size_t)NEDGES * 4;
  float* fold_ui = ws + o; o += 1024;
  float* fold_iu = ws + o; o += 1024;
  float* bns_u = ws + o; o += 512;
  float* bns_i = ws + o; o += 512;
  // CSR scratch (ints)
  int* deg_i    = (int*)(ws + o); o += NITEMS;
  int* deg_u    = (int*)(ws + o); o += NUSERS;
  int* rowptr_i = (int*)(ws + o); o += NITEMS + 1;
  int* rowptr_u = (int*)(ws + o); o += NUSERS + 1;
  int* cur_i    = (int*)(ws + o); o += NITEMS;
  int* cur_u    = (int*)(ws + o); o += NUSERS;
  int* bsum     = (int*)(ws + o); o += 256;
  int* csrsrc_i = (int*)(ws + o); o += NEDGES;
  int* csreid_i = (int*)(ws + o); o += NEDGES;
  int* csrsrc_u = (int*)(ws + o); o += NEDGES;
  int* csreid_u = (int*)(ws + o); o += NEDGES;

  const int gE = (NEDGES + 255) / 256;
  const int g_eh = (NEDGES * 4 + 255) / 256;
  const int nb_i = (NITEMS + 1023) / 1024;
  const int nb_u = (NUSERS + 1023) / 1024;

  // ---- build CSR once (edges identical across layers) ----
  hipMemsetAsync(deg_i, 0, NITEMS * sizeof(int), stream);
  hipMemsetAsync(deg_u, 0, NUSERS * sizeof(int), stream);
  hist_k<<<dim3(gE), dim3(256), 0, stream>>>(ei, deg_i);
  hist_k<<<dim3(gE), dim3(256), 0, stream>>>(eu, deg_u);
  scan1_k<<<dim3(nb_i), dim3(256), 0, stream>>>(deg_i, bsum, NITEMS);
  scan2_k<<<dim3(1), dim3(64), 0, stream>>>(bsum, nb_i);
  scan3_k<<<dim3(nb_i), dim3(256), 0, stream>>>(deg_i, bsum, rowptr_i, NITEMS);
  setval_k<<<dim3(1), dim3(1), 0, stream>>>(rowptr_i + NITEMS, NEDGES);
  scan1_k<<<dim3(nb_u), dim3(256), 0, stream>>>(deg_u, bsum, NUSERS);
  scan2_k<<<dim3(1), dim3(64), 0, stream>>>(bsum, nb_u);
  scan3_k<<<dim3(nb_u), dim3(256), 0, stream>>>(deg_u, bsum, rowptr_u, NUSERS);
  setval_k<<<dim3(1), dim3(1), 0, stream>>>(rowptr_u + NUSERS, NEDGES);
  copy_int_k<<<dim3((NITEMS + 255) / 256), dim3(256), 0, stream>>>(rowptr_i, cur_i, NITEMS);
  copy_int_k<<<dim3((NUSERS + 255) / 256), dim3(256), 0, stream>>>(rowptr_u, cur_u, NUSERS);
  scat_k<<<dim3(gE), dim3(256), 0, stream>>>(ei, eu, cur_i, csrsrc_i, csreid_i);
  scat_k<<<dim3(gE), dim3(256), 0, stream>>>(eu, ei, cur_u, csrsrc_u, csreid_u);

  const float* in_u = x_user;
  const float* in_i = x_item;
  int K = 128;

  for (int L = 0; L < 4; ++L) {
    const int H = 4;
    const int dh = (L == 3) ? 32 : 64;
    const int W = H * dh;
    const float* W_ui = Wm[L][0]; const float* A_ui = Am[L][0];
    const float* W_iu = Wm[L][1]; const float* A_iu = Am[L][1];

    // folded dst-side projections
    fold_k<<<dim3((K * H + 255) / 256), dim3(256), 0, stream>>>(W_ui, A_ui, fold_ui, K, H, dh);
    fold_k<<<dim3((K * H + 255) / 256), dim3(256), 0, stream>>>(W_iu, A_iu, fold_iu, K, H, dh);

    // src projections
    sgemm_k<<<dim3(W / 64, (NUSERS + 63) / 64), dim3(256), 0, stream>>>(in_u, W_ui, hs_u, NUSERS, W, K);
    sgemm_k<<<dim3(W / 64, (NITEMS + 63) / 64), dim3(256), 0, stream>>>(in_i, W_iu, hs_i, NITEMS, W, K);

    // er (dst side), el (src side)
    er_k<<<dim3(NITEMS), dim3(256), 0, stream>>>(in_i, fold_ui, er_i, K);
    er_k<<<dim3(NUSERS), dim3(256), 0, stream>>>(in_u, fold_iu, er_u, K);
    el_k<<<dim3(NUSERS), dim3(W), 0, stream>>>(hs_u, A_ui, el_u, H, dh);
    el_k<<<dim3(NITEMS), dim3(W), 0, stream>>>(hs_i, A_iu, el_i, H, dh);

    // zero softmax state (ordered-uint max identity == 0)
    hipMemsetAsync(m_u, 0, (size_t)NUSERS * 4 * sizeof(float), stream);
    hipMemsetAsync(s_u, 0, (size_t)NUSERS * 4 * sizeof(float), stream);
    hipMemsetAsync(m_i, 0, (size_t)NITEMS * 4 * sizeof(float), stream);
    hipMemsetAsync(s_i, 0, (size_t)NITEMS * 4 * sizeof(float), stream);

    float* agg_u; float* agg_i;
    if (L < 3) { agg_u = h_u; agg_i = h_i; }
    else { agg_u = out; agg_i = out + (size_t)NUSERS * 128; }

    // relation ui: src=user -> dst=item
    edge1_k<<<dim3(g_eh), dim3(256), 0, stream>>>(el_u, er_i, eu, ei, ebuf, m_i);
    edge2_k<<<dim3(g_eh), dim3(256), 0, stream>>>(ebuf, m_i, s_i, ei);
    gather_k<<<dim3(NITEMS), dim3(W), 0, stream>>>(ebuf, s_i, rowptr_i, csrsrc_i, csreid_i, hs_u, agg_i, W, dh);

    // relation iu: src=item -> dst=user
    edge1_k<<<dim3(g_eh), dim3(256), 0, stream>>>(el_i, er_u, ei, eu, ebuf, m_u);
    edge2_k<<<dim3(g_eh), dim3(256), 0, stream>>>(ebuf, m_u, s_u, eu);
    gather_k<<<dim3(NUSERS), dim3(W), 0, stream>>>(ebuf, s_u, rowptr_u, csrsrc_u, csreid_u, hs_i, agg_u, W, dh);

    if (L < 3) {
      hipMemsetAsync(bns_u, 0, 512 * sizeof(float), stream);
      hipMemsetAsync(bns_i, 0, 512 * sizeof(float), stream);
      bn_stats_k<<<dim3((NUSERS + 63) / 64), dim3(256), 0, stream>>>(agg_u, bns_u, NUSERS);
      bn_stats_k<<<dim3((NITEMS + 63) / 64), dim3(256), 0, stream>>>(agg_i, bns_i, NITEMS);
      bn_apply_k<<<dim3((NUSERS * 256 + 255) / 256), dim3(256), 0, stream>>>(agg_u, bns_u, bnu + L * 512, NUSERS, L == 2);
      bn_apply_k<<<dim3((NITEMS * 256 + 255) / 256), dim3(256), 0, stream>>>(agg_i, bns_i, bni + L * 512, NITEMS, L == 2);
      in_u = h_u; in_i = h_i; K = 256;
    }
  }
}

// Round 3
// 2172.273 us; speedup vs baseline: 1.9037x; 1.1936x over previous
//
#include <hip/hip_runtime.h>
#include <hip/hip_bf16.h>

#define NUSERS 50000
#define NITEMS 20000
#define NEDGES 400000

typedef __attribute__((ext_vector_type(8))) short bf16x8;
typedef __attribute__((ext_vector_type(4))) float f32x4;

// ---------- helpers ----------
__device__ __forceinline__ unsigned ford(float f) {
  unsigned b = __float_as_uint(f);
  return (b & 0x80000000u) ? ~b : (b | 0x80000000u);   // monotone float->uint
}
__device__ __forceinline__ float fdec(unsigned u) {
  return __uint_as_float((u & 0x80000000u) ? (u & 0x7FFFFFFFu) : ~u);
}

// ---------- fold: Wr[h*K+f] = sum_d W[f, h*dh+d] * A[1,h,d] ----------
__global__ void fold_k(const float* __restrict__ W, const float* __restrict__ A,
                       float* __restrict__ fold, int K, int H, int dh) {
  int t = blockIdx.x * blockDim.x + threadIdx.x;
  if (t >= K * H) return;
  int h = t / K, f = t - h * K;
  int HD = H * dh;
  const float* A1 = A + HD;
  float s = 0.f;
  for (int d = 0; d < dh; ++d) s += W[f * HD + h * dh + d] * A1[h * dh + d];
  fold[h * K + f] = s;
}

// ---------- W convert+transpose: Bt[n,k] = bf16(W[k,n]) ----------
__global__ void wcvt_k(const float* __restrict__ W, __hip_bfloat16* __restrict__ Bt,
                       int K, int Nw) {
  int t = blockIdx.x * blockDim.x + threadIdx.x;
  if (t >= K * Nw) return;
  int n = t / K, k = t - n * K;
  Bt[t] = __float2bfloat16(W[(long)k * Nw + n]);
}

// ---------- fp32 -> bf16 elementwise ----------
__global__ void xcvt_k(const float* __restrict__ x, __hip_bfloat16* __restrict__ y, long n) {
  long i = (long)blockIdx.x * blockDim.x + threadIdx.x;
  if (i < n) y[i] = __float2bfloat16(x[i]);
}

// ---------- bf16 MFMA GEMM: C[M,N] = A[M,K] @ Bt[N,K]^T ----------
// block 256 = 4 waves (2x2), wave tile 64x64 (4x4 of 16x16x32), block tile 128x128, BK=32
__global__ __launch_bounds__(256) void hgemm_k(const __hip_bfloat16* __restrict__ A,
                                               const __hip_bfloat16* __restrict__ Bt,
                                               __hip_bfloat16* __restrict__ C,
                                               int M, int N, int K) {
  __shared__ __hip_bfloat16 As[128 * 32];
  __shared__ __hip_bfloat16 Bs[128 * 32];
  int tid = threadIdx.x;
  int row0 = blockIdx.y * 128, col0 = blockIdx.x * 128;
  int lane = tid & 63, wv = tid >> 6;
  int wr = (wv & 1) * 64, wc = (wv >> 1) * 64;
  int l16 = lane & 15, q = lane >> 4;
  f32x4 acc[4][4] = {};
  int r = tid >> 2, c8 = (tid & 3) * 8;   // staging: 8 bf16 per thread per chunk
  for (int k0 = 0; k0 < K; k0 += 32) {
    int ra = min(row0 + r, M - 1);
    uint4 va = *(const uint4*)&A[(long)ra * K + k0 + c8];
    int ra2 = min(row0 + r + 64, M - 1);
    uint4 va2 = *(const uint4*)&A[(long)ra2 * K + k0 + c8];
    uint4 vb = *(const uint4*)&Bt[(long)(col0 + r) * K + k0 + c8];
    uint4 vb2 = *(const uint4*)&Bt[(long)(col0 + r + 64) * K + k0 + c8];
    *(uint4*)&As[r * 32 + c8] = va;
    *(uint4*)&As[(r + 64) * 32 + c8] = va2;
    *(uint4*)&Bs[r * 32 + c8] = vb;
    *(uint4*)&Bs[(r + 64) * 32 + c8] = vb2;
    __syncthreads();
    bf16x8 af[4], bfr[4];
#pragma unroll
    for (int i = 0; i < 4; ++i) {
      af[i] = *(const bf16x8*)&As[(wr + i * 16 + l16) * 32 + q * 8];
      bfr[i] = *(const bf16x8*)&Bs[(wc + i * 16 + l16) * 32 + q * 8];
    }
#pragma unroll
    for (int i = 0; i < 4; ++i)
#pragma unroll
      for (int j = 0; j < 4; ++j)
        acc[i][j] = __builtin_amdgcn_mfma_f32_16x16x32_bf16(af[i], bfr[j], acc[i][j], 0, 0, 0);
    __syncthreads();
  }
  // C/D layout: col = lane&15, row = (lane>>4)*4 + reg
#pragma unroll
  for (int i = 0; i < 4; ++i) {
#pragma unroll
    for (int reg = 0; reg < 4; ++reg) {
      int rr = row0 + wr + i * 16 + q * 4 + reg;
      if (rr < M) {
#pragma unroll
        for (int j = 0; j < 4; ++j)
          C[(long)rr * N + col0 + wc + j * 16 + l16] = __float2bfloat16(acc[i][j][reg]);
      }
    }
  }
}

// ---------- er: er[n,h] = x[n,:] @ fold[h,:]  (H=4, block=256) ----------
__global__ __launch_bounds__(256) void er_k(const __hip_bfloat16* __restrict__ X,
                                            const float* __restrict__ fold,
                                            float* __restrict__ er, int K) {
  __shared__ float xs[256];
  int n = blockIdx.x, t = threadIdx.x;
  if (t < K) xs[t] = __bfloat162float(X[(long)n * K + t]);
  __syncthreads();
  int h = t >> 6, l = t & 63;
  float p = 0.f;
  for (int f = l; f < K; f += 64) p += xs[f] * fold[h * K + f];
#pragma unroll
  for (int off = 32; off; off >>= 1) p += __shfl_down(p, off, 64);
  if (l == 0) er[n * 4 + h] = p;
}

// ---------- el: el[n,h] = hs[n,h,:] . A0[h,:]  (block = H*dh) ----------
__global__ void el_k(const __hip_bfloat16* __restrict__ hs, const float* __restrict__ A0,
                     float* __restrict__ el, int H, int dh) {
  int n = blockIdx.x, t = threadIdx.x;
  int W = blockDim.x;
  float v = __bfloat162float(hs[(long)n * W + t]) * A0[t];
  for (int off = dh >> 1; off; off >>= 1) v += __shfl_down(v, off, dh);
  if ((t & (dh - 1)) == 0) el[n * H + t / dh] = v;
}

// ---------- edge pass 1: logits + segment max ----------
__global__ void edge1_k(const float* __restrict__ el, const float* __restrict__ er,
                        const int* __restrict__ src, const int* __restrict__ dst,
                        float* __restrict__ ebuf, unsigned* __restrict__ mbuf) {
  int idx = blockIdx.x * blockDim.x + threadIdx.x;
  if (idx >= NEDGES * 4) return;
  int e = idx >> 2, h = idx & 3;
  float v = el[src[e] * 4 + h] + er[dst[e] * 4 + h];
  v = (v > 0.f) ? v : 0.2f * v;              // attn leaky_relu, slope 0.2
  ebuf[idx] = v;
  atomicMax(&mbuf[dst[e] * 4 + h], ford(v));
}

// ---------- edge pass 2: exp + segment sum ----------
__global__ void edge2_k(float* __restrict__ ebuf, const unsigned* __restrict__ mbuf,
                        float* __restrict__ sbuf, const int* __restrict__ dst) {
  int idx = blockIdx.x * blockDim.x + threadIdx.x;
  if (idx >= NEDGES * 4) return;
  int e = idx >> 2, h = idx & 3;
  int d = dst[e];
  float ee = expf(ebuf[idx] - fdec(mbuf[d * 4 + h]));
  ebuf[idx] = ee;
  atomicAdd(&sbuf[d * 4 + h], ee);
}

// ---------- CSR build ----------
__global__ void hist_k(const int* __restrict__ dst, int* __restrict__ deg) {
  int e = blockIdx.x * blockDim.x + threadIdx.x;
  if (e < NEDGES) atomicAdd(&deg[dst[e]], 1);
}

__global__ __launch_bounds__(256) void scan1_k(const int* __restrict__ deg,
                                               int* __restrict__ bsum, int N) {
  __shared__ int red[256];
  int base = blockIdx.x * 1024, t = threadIdx.x;
  int s = 0;
#pragma unroll
  for (int j = 0; j < 4; ++j) { int i = base + t * 4 + j; s += (i < N) ? deg[i] : 0; }
  red[t] = s; __syncthreads();
  for (int off = 128; off; off >>= 1) { if (t < off) red[t] += red[t + off]; __syncthreads(); }
  if (t == 0) bsum[blockIdx.x] = red[0];
}

__global__ void scan2_k(int* __restrict__ bsum, int nb) {
  if (threadIdx.x == 0) {
    int run = 0;
    for (int i = 0; i < nb; ++i) { int v = bsum[i]; bsum[i] = run; run += v; }
  }
}

__global__ __launch_bounds__(256) void scan3_k(const int* __restrict__ deg,
                                               const int* __restrict__ bsum,
                                               int* __restrict__ rowptr, int N) {
  __shared__ int tsum[256];
  int base = blockIdx.x * 1024, t = threadIdx.x;
  int v[4]; int s = 0;
#pragma unroll
  for (int j = 0; j < 4; ++j) { int i = base + t * 4 + j; v[j] = (i < N) ? deg[i] : 0; s += v[j]; }
  tsum[t] = s; __syncthreads();
  for (int off = 1; off < 256; off <<= 1) {
    int x = (t >= off) ? tsum[t - off] : 0;
    __syncthreads();
    tsum[t] += x;
    __syncthreads();
  }
  int run = bsum[blockIdx.x] + ((t > 0) ? tsum[t - 1] : 0);
#pragma unroll
  for (int j = 0; j < 4; ++j) {
    int i = base + t * 4 + j;
    if (i < N) rowptr[i] = run;
    run += v[j];
  }
}

__global__ void setval_k(int* __restrict__ p, int v) { *p = v; }

__global__ void copy_int_k(const int* __restrict__ a, int* __restrict__ b, int N) {
  int i = blockIdx.x * blockDim.x + threadIdx.x;
  if (i < N) b[i] = a[i];
}

__global__ void scat_k(const int* __restrict__ dst, const int* __restrict__ src,
                       int* __restrict__ cursor, int* __restrict__ csr_src,
                       int* __restrict__ csr_eid) {
  int e = blockIdx.x * blockDim.x + threadIdx.x;
  if (e >= NEDGES) return;
  int d = dst[e];
  int p = atomicAdd(&cursor[d], 1);
  csr_src[p] = src[e];
  csr_eid[p] = e;
}

// ---------- fused normalize + CSR gather aggregate (bf16 hs) ----------
__global__ void gather_k(const float* __restrict__ ebuf, const float* __restrict__ sbuf,
                         const int* __restrict__ rowptr, const int* __restrict__ csr_src,
                         const int* __restrict__ csr_eid, const __hip_bfloat16* __restrict__ hs,
                         float* __restrict__ outbuf, int W, int dh) {
  int d = blockIdx.x;
  int c = threadIdx.x;
  int h = c / dh;
  int s0 = rowptr[d], s1 = rowptr[d + 1];
  float acc = 0.f;
  for (int k = s0; k < s1; ++k) {
    int s = csr_src[k];
    int e = csr_eid[k];
    acc += ebuf[e * 4 + h] * __bfloat162float(hs[(long)s * W + c]);
  }
  float inv = (s1 > s0) ? 1.0f / sbuf[d * 4 + h] : 0.0f;
  outbuf[(long)d * W + c] = acc * inv;
}

// ---------- BN stats: column sum / sumsq (C=256) ----------
__global__ __launch_bounds__(256) void bn_stats_k(const float* __restrict__ x,
                                                  float* __restrict__ sums, int N) {
  const int C = 256;
  int c = threadIdx.x;
  int r0 = blockIdx.x * 64;
  int r1 = min(r0 + 64, N);
  float s = 0.f, s2 = 0.f;
  for (int r = r0; r < r1; ++r) {
    float v = x[(long)r * C + c];
    s += v; s2 += v * v;
  }
  atomicAdd(&sums[c], s);
  atomicAdd(&sums[C + c], s2);
}

// ---------- BN apply + activation -> bf16 ----------
__global__ void bn_apply_k(const float* __restrict__ x, const float* __restrict__ sums,
                           const float* __restrict__ gb, __hip_bfloat16* __restrict__ xo,
                           int N, int act) {
  const int C = 256;
  int idx = blockIdx.x * blockDim.x + threadIdx.x;
  if (idx >= N * C) return;
  int c = idx & 255;
  float inv_n = 1.0f / (float)N;
  float mean = sums[c] * inv_n;
  float var = sums[C + c] * inv_n - mean * mean;
  float v = gb[c] * (x[idx] - mean) * rsqrtf(var + 1e-5f) + gb[C + c];
  v = act ? tanhf(v) : (v > 0.f ? v : 0.01f * v);
  xo[idx] = __float2bfloat16(v);
}

extern "C" void kernel_launch(void* const* d_in, const int* in_sizes, int n_in,
                              void* d_out, int out_size, void* d_ws, size_t ws_size,
                              hipStream_t stream) {
  const float* x_user = (const float*)d_in[0];
  const float* x_item = (const float*)d_in[1];
  const int* eu = (const int*)d_in[2];
  const int* ei = (const int*)d_in[3];
  const float *Wm[4][2], *Am[4][2];
  for (int L = 0; L < 4; ++L) {
    Wm[L][0] = (const float*)d_in[4 + L * 4 + 0];
    Am[L][0] = (const float*)d_in[4 + L * 4 + 1];
    Wm[L][1] = (const float*)d_in[4 + L * 4 + 2];
    Am[L][1] = (const float*)d_in[4 + L * 4 + 3];
  }
  const float* bnu = (const float*)d_in[20];
  const float* bni = (const float*)d_in[21];
  float* out = (float*)d_out;

  float* ws = (float*)d_ws;
  size_t o = 0;
  float* agg_u = ws + o; o += (size_t)NUSERS * 256;   // fp32 aggregation (pre-BN)
  float* agg_i = ws + o; o += (size_t)NITEMS * 256;
  float* el_u = ws + o; o += (size_t)NUSERS * 4;
  float* er_u = ws + o; o += (size_t)NUSERS * 4;
  float* s_u = ws + o;  o += (size_t)NUSERS * 4;
  unsigned* m_u = (unsigned*)(ws + o); o += (size_t)NUSERS * 4;
  float* el_i = ws + o; o += (size_t)NITEMS * 4;
  float* er_i = ws + o; o += (size_t)NITEMS * 4;
  float* s_i = ws + o;  o += (size_t)NITEMS * 4;
  unsigned* m_i = (unsigned*)(ws + o); o += (size_t)NITEMS * 4;
  float* ebuf = ws + o; o += (size_t)NEDGES * 4;
  float* fold_ui = ws + o; o += 1024;
  float* fold_iu = ws + o; o += 1024;
  float* bns_u = ws + o; o += 512;
  float* bns_i = ws + o; o += 512;
  // bf16 buffers (allocated in float-sized units; all 16B-aligned offsets)
  __hip_bfloat16* hb_u  = (__hip_bfloat16*)(ws + o); o += (size_t)NUSERS * 128;  // [NU,256] bf16
  __hip_bfloat16* hb_i  = (__hip_bfloat16*)(ws + o); o += (size_t)NITEMS * 128;
  __hip_bfloat16* hsb_u = (__hip_bfloat16*)(ws + o); o += (size_t)NUSERS * 128;
  __hip_bfloat16* hsb_i = (__hip_bfloat16*)(ws + o); o += (size_t)NITEMS * 128;
  __hip_bfloat16* Bt_ui = (__hip_bfloat16*)(ws + o); o += 32768;  // 256*256 bf16
  __hip_bfloat16* Bt_iu = (__hip_bfloat16*)(ws + o); o += 32768;
  // CSR scratch (ints)
  int* deg_i    = (int*)(ws + o); o += NITEMS;
  int* deg_u    = (int*)(ws + o); o += NUSERS;
  int* rowptr_i = (int*)(ws + o); o += NITEMS + 1;
  int* rowptr_u = (int*)(ws + o); o += NUSERS + 1;
  int* cur_i    = (int*)(ws + o); o += NITEMS;
  int* cur_u    = (int*)(ws + o); o += NUSERS;
  int* bsum     = (int*)(ws + o); o += 256;
  int* csrsrc_i = (int*)(ws + o); o += NEDGES;
  int* csreid_i = (int*)(ws + o); o += NEDGES;
  int* csrsrc_u = (int*)(ws + o); o += NEDGES;
  int* csreid_u = (int*)(ws + o); o += NEDGES;

  const int gE = (NEDGES + 255) / 256;
  const int g_eh = (NEDGES * 4 + 255) / 256;
  const int nb_i = (NITEMS + 1023) / 1024;
  const int nb_u = (NUSERS + 1023) / 1024;

  // ---- build CSR once (edges identical across layers) ----
  hipMemsetAsync(deg_i, 0, NITEMS * sizeof(int), stream);
  hipMemsetAsync(deg_u, 0, NUSERS * sizeof(int), stream);
  hist_k<<<dim3(gE), dim3(256), 0, stream>>>(ei, deg_i);
  hist_k<<<dim3(gE), dim3(256), 0, stream>>>(eu, deg_u);
  scan1_k<<<dim3(nb_i), dim3(256), 0, stream>>>(deg_i, bsum, NITEMS);
  scan2_k<<<dim3(1), dim3(64), 0, stream>>>(bsum, nb_i);
  scan3_k<<<dim3(nb_i), dim3(256), 0, stream>>>(deg_i, bsum, rowptr_i, NITEMS);
  setval_k<<<dim3(1), dim3(1), 0, stream>>>(rowptr_i + NITEMS, NEDGES);
  scan1_k<<<dim3(nb_u), dim3(256), 0, stream>>>(deg_u, bsum, NUSERS);
  scan2_k<<<dim3(1), dim3(64), 0, stream>>>(bsum, nb_u);
  scan3_k<<<dim3(nb_u), dim3(256), 0, stream>>>(deg_u, bsum, rowptr_u, NUSERS);
  setval_k<<<dim3(1), dim3(1), 0, stream>>>(rowptr_u + NUSERS, NEDGES);
  copy_int_k<<<dim3((NITEMS + 255) / 256), dim3(256), 0, stream>>>(rowptr_i, cur_i, NITEMS);
  copy_int_k<<<dim3((NUSERS + 255) / 256), dim3(256), 0, stream>>>(rowptr_u, cur_u, NUSERS);
  scat_k<<<dim3(gE), dim3(256), 0, stream>>>(ei, eu, cur_i, csrsrc_i, csreid_i);
  scat_k<<<dim3(gE), dim3(256), 0, stream>>>(eu, ei, cur_u, csrsrc_u, csreid_u);

  // layer-0 inputs -> bf16
  xcvt_k<<<dim3((NUSERS * 128 + 255) / 256), dim3(256), 0, stream>>>(x_user, hb_u, (long)NUSERS * 128);
  xcvt_k<<<dim3((NITEMS * 128 + 255) / 256), dim3(256), 0, stream>>>(x_item, hb_i, (long)NITEMS * 128);

  int K = 128;

  for (int L = 0; L < 4; ++L) {
    const int H = 4;
    const int dh = (L == 3) ? 32 : 64;
    const int W = H * dh;
    const float* W_ui = Wm[L][0]; const float* A_ui = Am[L][0];
    const float* W_iu = Wm[L][1]; const float* A_iu = Am[L][1];

    // folded dst-side projections + weight transpose/convert
    fold_k<<<dim3((K * H + 255) / 256), dim3(256), 0, stream>>>(W_ui, A_ui, fold_ui, K, H, dh);
    fold_k<<<dim3((K * H + 255) / 256), dim3(256), 0, stream>>>(W_iu, A_iu, fold_iu, K, H, dh);
    wcvt_k<<<dim3((K * W + 255) / 256), dim3(256), 0, stream>>>(W_ui, Bt_ui, K, W);
    wcvt_k<<<dim3((K * W + 255) / 256), dim3(256), 0, stream>>>(W_iu, Bt_iu, K, W);

    // src projections (bf16 MFMA)
    hgemm_k<<<dim3(W / 128, (NUSERS + 127) / 128), dim3(256), 0, stream>>>(hb_u, Bt_ui, hsb_u, NUSERS, W, K);
    hgemm_k<<<dim3(W / 128, (NITEMS + 127) / 128), dim3(256), 0, stream>>>(hb_i, Bt_iu, hsb_i, NITEMS, W, K);

    // er (dst side), el (src side)
    er_k<<<dim3(NITEMS), dim3(256), 0, stream>>>(hb_i, fold_ui, er_i, K);
    er_k<<<dim3(NUSERS), dim3(256), 0, stream>>>(hb_u, fold_iu, er_u, K);
    el_k<<<dim3(NUSERS), dim3(W), 0, stream>>>(hsb_u, A_ui, el_u, H, dh);
    el_k<<<dim3(NITEMS), dim3(W), 0, stream>>>(hsb_i, A_iu, el_i, H, dh);

    // zero softmax state (ordered-uint max identity == 0)
    hipMemsetAsync(m_u, 0, (size_t)NUSERS * 4 * sizeof(float), stream);
    hipMemsetAsync(s_u, 0, (size_t)NUSERS * 4 * sizeof(float), stream);
    hipMemsetAsync(m_i, 0, (size_t)NITEMS * 4 * sizeof(float), stream);
    hipMemsetAsync(s_i, 0, (size_t)NITEMS * 4 * sizeof(float), stream);

    float* dst_u; float* dst_i;
    if (L < 3) { dst_u = agg_u; dst_i = agg_i; }
    else { dst_u = out; dst_i = out + (size_t)NUSERS * 128; }

    // relation ui: src=user -> dst=item
    edge1_k<<<dim3(g_eh), dim3(256), 0, stream>>>(el_u, er_i, eu, ei, ebuf, m_i);
    edge2_k<<<dim3(g_eh), dim3(256), 0, stream>>>(ebuf, m_i, s_i, ei);
    gather_k<<<dim3(NITEMS), dim3(W), 0, stream>>>(ebuf, s_i, rowptr_i, csrsrc_i, csreid_i, hsb_u, dst_i, W, dh);

    // relation iu: src=item -> dst=user
    edge1_k<<<dim3(g_eh), dim3(256), 0, stream>>>(el_i, er_u, ei, eu, ebuf, m_u);
    edge2_k<<<dim3(g_eh), dim3(256), 0, stream>>>(ebuf, m_u, s_u, eu);
    gather_k<<<dim3(NUSERS), dim3(W), 0, stream>>>(ebuf, s_u, rowptr_u, csrsrc_u, csreid_u, hsb_i, dst_u, W, dh);

    if (L < 3) {
      hipMemsetAsync(bns_u, 0, 512 * sizeof(float), stream);
      hipMemsetAsync(bns_i, 0, 512 * sizeof(float), stream);
      bn_stats_k<<<dim3((NUSERS + 63) / 64), dim3(256), 0, stream>>>(agg_u, bns_u, NUSERS);
      bn_stats_k<<<dim3((NITEMS + 63) / 64), dim3(256), 0, stream>>>(agg_i, bns_i, NITEMS);
      bn_apply_k<<<dim3((NUSERS * 256 + 255) / 256), dim3(256), 0, stream>>>(agg_u, bns_u, bnu + L * 512, hb_u, NUSERS, L == 2);
      bn_apply_k<<<dim3((NITEMS * 256 + 255) / 256), dim3(256), 0, stream>>>(agg_i, bns_i, bni + L * 512, hb_i, NITEMS, L == 2);
      K = 256;
    }
  }
}

// Round 4
// 1374.652 us; speedup vs baseline: 3.0083x; 1.5802x over previous
//
#include <hip/hip_runtime.h>

#define NUSERS 50000
#define NITEMS 20000
#define NEDGES 400000

typedef _Float16 f16;
typedef __attribute__((ext_vector_type(8))) _Float16 f16x8;
typedef __attribute__((ext_vector_type(4))) _Float16 f16x4;
typedef __attribute__((ext_vector_type(2))) _Float16 f16x2;
typedef __attribute__((ext_vector_type(4))) float f32x4;

// ---------- prep: weight transpose->f16 + folded dst projection, both relations ----------
// Bt[n*K+k] = f16(W[k*Nw+n]);  fold[h*K+f] = sum_d W[f*Nw + h*dh + d] * A[1][h][d]
__global__ void prep_k(const float* __restrict__ Wa, const float* __restrict__ Aa,
                       f16* __restrict__ Bta, float* __restrict__ folda,
                       const float* __restrict__ Wb, const float* __restrict__ Ab,
                       f16* __restrict__ Btb, float* __restrict__ foldb,
                       int K, int Nw, int dh) {
  int t = blockIdx.x * blockDim.x + threadIdx.x;
  int half = K * Nw;
  if (t >= 2 * half) return;
  const float* W = (t < half) ? Wa : Wb;
  const float* A = (t < half) ? Aa : Ab;
  f16* Bt = (t < half) ? Bta : Btb;
  float* fold = (t < half) ? folda : foldb;
  int t2 = (t < half) ? t : t - half;
  int n = t2 / K, k = t2 - n * K;
  Bt[t2] = (f16)W[(long)k * Nw + n];
  if (t2 < K * 4) {
    int h = t2 / K, f = t2 - h * K;
    const float* A1 = A + Nw;          // A[1]
    float s = 0.f;
    for (int d = 0; d < dh; ++d) s += W[f * Nw + h * dh + d] * A1[h * dh + d];
    fold[h * K + f] = s;
  }
}

// ---------- fp32 -> f16 convert, both sides in one launch ----------
__global__ void xcvt_k(const float* __restrict__ xu, f16* __restrict__ yu, long nu,
                       const float* __restrict__ xi, f16* __restrict__ yi, long ni) {
  long i = (long)blockIdx.x * blockDim.x + threadIdx.x;
  if (i < nu) yu[i] = (f16)xu[i];
  else if (i < nu + ni) yi[i - nu] = (f16)xi[i - nu];
}

// ---------- f16 MFMA GEMM, user+item fused: C = A[M,K] @ Bt[N,K]^T ----------
// block 256 = 4 waves (2x2), wave tile 64x64 (4x4 of 16x16x32), block tile 128x128, BK=32
__global__ __launch_bounds__(256) void hgemm2_k(const f16* __restrict__ Aa, const f16* __restrict__ Bta,
                                                f16* __restrict__ Ca, int Ma, int gya,
                                                const f16* __restrict__ Ab, const f16* __restrict__ Btb,
                                                f16* __restrict__ Cb, int Mb,
                                                int N, int K) {
  __shared__ f16 As[128 * 32];
  __shared__ f16 Bs[128 * 32];
  int by = blockIdx.y;
  const f16* A; const f16* Bt; f16* C; int M; int row0;
  if (by < gya) { A = Aa; Bt = Bta; C = Ca; M = Ma; row0 = by * 128; }
  else          { A = Ab; Bt = Btb; C = Cb; M = Mb; row0 = (by - gya) * 128; }
  int tid = threadIdx.x;
  int col0 = blockIdx.x * 128;
  int lane = tid & 63, wv = tid >> 6;
  int wr = (wv & 1) * 64, wc = (wv >> 1) * 64;
  int l16 = lane & 15, q = lane >> 4;
  f32x4 acc[4][4] = {};
  int r = tid >> 2, c8 = (tid & 3) * 8;
  for (int k0 = 0; k0 < K; k0 += 32) {
    int ra = min(row0 + r, M - 1);
    uint4 va = *(const uint4*)&A[(long)ra * K + k0 + c8];
    int ra2 = min(row0 + r + 64, M - 1);
    uint4 va2 = *(const uint4*)&A[(long)ra2 * K + k0 + c8];
    uint4 vb = *(const uint4*)&Bt[(long)(col0 + r) * K + k0 + c8];
    uint4 vb2 = *(const uint4*)&Bt[(long)(col0 + r + 64) * K + k0 + c8];
    *(uint4*)&As[r * 32 + c8] = va;
    *(uint4*)&As[(r + 64) * 32 + c8] = va2;
    *(uint4*)&Bs[r * 32 + c8] = vb;
    *(uint4*)&Bs[(r + 64) * 32 + c8] = vb2;
    __syncthreads();
    f16x8 af[4], bfr[4];
#pragma unroll
    for (int i = 0; i < 4; ++i) {
      af[i] = *(const f16x8*)&As[(wr + i * 16 + l16) * 32 + q * 8];
      bfr[i] = *(const f16x8*)&Bs[(wc + i * 16 + l16) * 32 + q * 8];
    }
#pragma unroll
    for (int i = 0; i < 4; ++i)
#pragma unroll
      for (int j = 0; j < 4; ++j)
        acc[i][j] = __builtin_amdgcn_mfma_f32_16x16x32_f16(af[i], bfr[j], acc[i][j], 0, 0, 0);
    __syncthreads();
  }
  // C/D layout: col = lane&15, row = (lane>>4)*4 + reg
#pragma unroll
  for (int i = 0; i < 4; ++i) {
#pragma unroll
    for (int reg = 0; reg < 4; ++reg) {
      int rr = row0 + wr + i * 16 + q * 4 + reg;
      if (rr < M) {
#pragma unroll
        for (int j = 0; j < 4; ++j)
          C[(long)rr * N + col0 + wc + j * 16 + l16] = (f16)acc[i][j][reg];
      }
    }
  }
}

// ---------- el+er fused, user+item in one launch (block per node) ----------
__global__ __launch_bounds__(256) void eler2_k(
    const f16* __restrict__ hsu, const float* __restrict__ A0u, const f16* __restrict__ hbu,
    const float* __restrict__ foldu, float* __restrict__ elu, float* __restrict__ eru,
    const f16* __restrict__ hsi, const float* __restrict__ A0i, const f16* __restrict__ hbi,
    const float* __restrict__ foldi, float* __restrict__ eli, float* __restrict__ eri,
    int W, int dh, int K) {
  __shared__ float xs[256];
  int b = blockIdx.x, t = threadIdx.x;
  const f16* hs; const float* A0; const f16* hb; const float* fold; float* el; float* er; int n;
  if (b < NUSERS) { hs = hsu; A0 = A0u; hb = hbu; fold = foldu; el = elu; er = eru; n = b; }
  else            { hs = hsi; A0 = A0i; hb = hbi; fold = foldi; el = eli; er = eri; n = b - NUSERS; }
  // el: t covers W channels, reduce per dh group
  float v = 0.f;
  if (t < W) v = (float)hs[(long)n * W + t] * A0[t];
  for (int off = dh >> 1; off; off >>= 1) v += __shfl_down(v, off);
  if (t < W && (t & (dh - 1)) == 0) el[n * 4 + t / dh] = v;
  // er: h row through fold
  if (t < K) xs[t] = (float)hb[(long)n * K + t];
  __syncthreads();
  int h = t >> 6, l = t & 63;
  float p = 0.f;
  for (int f = l; f < K; f += 64) p += xs[f] * fold[h * K + f];
#pragma unroll
  for (int off = 32; off; off >>= 1) p += __shfl_down(p, off);
  if (l == 0) er[n * 4 + h] = p;
}

// ---------- CSR build ----------
__global__ void hist_k(const int* __restrict__ ei, int* __restrict__ degi,
                       const int* __restrict__ eu, int* __restrict__ degu) {
  int e = blockIdx.x * blockDim.x + threadIdx.x;
  if (e < NEDGES) atomicAdd(&degi[ei[e]], 1);
  else if (e < 2 * NEDGES) atomicAdd(&degu[eu[e - NEDGES]], 1);
}

__global__ __launch_bounds__(256) void scan1_k(const int* __restrict__ deg,
                                               int* __restrict__ bsum, int N) {
  __shared__ int red[256];
  int base = blockIdx.x * 1024, t = threadIdx.x;
  int s = 0;
#pragma unroll
  for (int j = 0; j < 4; ++j) { int i = base + t * 4 + j; s += (i < N) ? deg[i] : 0; }
  red[t] = s; __syncthreads();
  for (int off = 128; off; off >>= 1) { if (t < off) red[t] += red[t + off]; __syncthreads(); }
  if (t == 0) bsum[blockIdx.x] = red[0];
}

__global__ void scan2_k(int* __restrict__ bsum, int nb) {
  if (threadIdx.x == 0) {
    int run = 0;
    for (int i = 0; i < nb; ++i) { int v = bsum[i]; bsum[i] = run; run += v; }
  }
}

__global__ __launch_bounds__(256) void scan3_k(const int* __restrict__ deg,
                                               const int* __restrict__ bsum,
                                               int* __restrict__ rowptr, int N) {
  __shared__ int tsum[256];
  int base = blockIdx.x * 1024, t = threadIdx.x;
  int v[4]; int s = 0;
#pragma unroll
  for (int j = 0; j < 4; ++j) { int i = base + t * 4 + j; v[j] = (i < N) ? deg[i] : 0; s += v[j]; }
  tsum[t] = s; __syncthreads();
  for (int off = 1; off < 256; off <<= 1) {
    int x = (t >= off) ? tsum[t - off] : 0;
    __syncthreads();
    tsum[t] += x;
    __syncthreads();
  }
  int run = bsum[blockIdx.x] + ((t > 0) ? tsum[t - 1] : 0);
#pragma unroll
  for (int j = 0; j < 4; ++j) {
    int i = base + t * 4 + j;
    if (i < N) rowptr[i] = run;
    run += v[j];
  }
}

__global__ void setval_k(int* __restrict__ p, int v) { *p = v; }

__global__ void copy2_k(const int* __restrict__ a, int* __restrict__ b, int Na,
                        const int* __restrict__ c, int* __restrict__ d, int Nc) {
  int i = blockIdx.x * blockDim.x + threadIdx.x;
  if (i < Na) b[i] = a[i];
  else if (i < Na + Nc) d[i - Na] = c[i - Na];
}

__global__ void scat_k(const int* __restrict__ ei, const int* __restrict__ eu,
                       int* __restrict__ curi, int* __restrict__ srci,
                       int* __restrict__ curu, int* __restrict__ srcu) {
  int e = blockIdx.x * blockDim.x + threadIdx.x;
  if (e < NEDGES) {
    int p = atomicAdd(&curi[ei[e]], 1);
    srci[p] = eu[e];
  } else if (e < 2 * NEDGES) {
    int e2 = e - NEDGES;
    int p = atomicAdd(&curu[eu[e2]], 1);
    srcu[p] = ei[e2];
  }
}

// ---------- fused segment-softmax + gather aggregate; both relations, wave per dst ----------
__global__ __launch_bounds__(256) void agg_k(
    const float* __restrict__ elA, const float* __restrict__ erA,
    const int* __restrict__ rpA, const int* __restrict__ srcA,
    const f16* __restrict__ hsA, float* __restrict__ outA, int nA,
    const float* __restrict__ elB, const float* __restrict__ erB,
    const int* __restrict__ rpB, const int* __restrict__ srcB,
    const f16* __restrict__ hsB, float* __restrict__ outB, int nB,
    int W, int dh) {
  int g = blockIdx.x * 4 + (threadIdx.x >> 6);
  int lane = threadIdx.x & 63;
  const float* el; const float* er; const int* rp; const int* srcv;
  const f16* hs; float* outp; int d;
  if (g < nA)           { el = elA; er = erA; rp = rpA; srcv = srcA; hs = hsA; outp = outA; d = g; }
  else if (g < nA + nB) { el = elB; er = erB; rp = rpB; srcv = srcB; hs = hsB; outp = outB; d = g - nA; }
  else return;
  int s0 = rp[d], s1 = rp[d + 1];
  int cpl = W >> 6;            // channels per lane: 4 (W=256) or 2 (W=128)
  int c0 = lane * cpl;
  int h = c0 / dh;
  float4 er4 = *(const float4*)&er[d * 4];
  const float NEG = -3.0e38f;
  float m0 = NEG, m1 = NEG, m2 = NEG, m3 = NEG;
  for (int k = s0 + lane; k < s1; k += 64) {
    int s = srcv[k];
    float4 e4 = *(const float4*)&el[s * 4];
    float v;
    v = e4.x + er4.x; v = v > 0.f ? v : 0.2f * v; m0 = fmaxf(m0, v);
    v = e4.y + er4.y; v = v > 0.f ? v : 0.2f * v; m1 = fmaxf(m1, v);
    v = e4.z + er4.z; v = v > 0.f ? v : 0.2f * v; m2 = fmaxf(m2, v);
    v = e4.w + er4.w; v = v > 0.f ? v : 0.2f * v; m3 = fmaxf(m3, v);
  }
#pragma unroll
  for (int off = 32; off; off >>= 1) {
    m0 = fmaxf(m0, __shfl_xor(m0, off));
    m1 = fmaxf(m1, __shfl_xor(m1, off));
    m2 = fmaxf(m2, __shfl_xor(m2, off));
    m3 = fmaxf(m3, __shfl_xor(m3, off));
  }
  float t0 = 0.f, t1 = 0.f, t2 = 0.f, t3 = 0.f;
  for (int k = s0 + lane; k < s1; k += 64) {
    int s = srcv[k];
    float4 e4 = *(const float4*)&el[s * 4];
    float v;
    v = e4.x + er4.x; v = v > 0.f ? v : 0.2f * v; t0 += expf(v - m0);
    v = e4.y + er4.y; v = v > 0.f ? v : 0.2f * v; t1 += expf(v - m1);
    v = e4.z + er4.z; v = v > 0.f ? v : 0.2f * v; t2 += expf(v - m2);
    v = e4.w + er4.w; v = v > 0.f ? v : 0.2f * v; t3 += expf(v - m3);
  }
#pragma unroll
  for (int off = 32; off; off >>= 1) {
    t0 += __shfl_xor(t0, off);
    t1 += __shfl_xor(t1, off);
    t2 += __shfl_xor(t2, off);
    t3 += __shfl_xor(t3, off);
  }
  float mh = h < 2 ? (h == 0 ? m0 : m1) : (h == 2 ? m2 : m3);
  float sh = h < 2 ? (h == 0 ? t0 : t1) : (h == 2 ? t2 : t3);
  float erh = h < 2 ? (h == 0 ? er4.x : er4.y) : (h == 2 ? er4.z : er4.w);
  float inv = (s1 > s0) ? 1.0f / sh : 0.0f;
  if (cpl == 4) {
    float a0 = 0.f, a1 = 0.f, a2 = 0.f, a3 = 0.f;
    for (int k = s0; k < s1; ++k) {
      int s = srcv[k];
      float v = el[s * 4 + h] + erh; v = v > 0.f ? v : 0.2f * v;
      float a = expf(v - mh);
      f16x4 hv = *(const f16x4*)&hs[(long)s * W + c0];
      a0 += a * (float)hv[0]; a1 += a * (float)hv[1];
      a2 += a * (float)hv[2]; a3 += a * (float)hv[3];
    }
    float4 o = make_float4(a0 * inv, a1 * inv, a2 * inv, a3 * inv);
    *(float4*)&outp[(long)d * W + c0] = o;
  } else {
    float a0 = 0.f, a1 = 0.f;
    for (int k = s0; k < s1; ++k) {
      int s = srcv[k];
      float v = el[s * 4 + h] + erh; v = v > 0.f ? v : 0.2f * v;
      float a = expf(v - mh);
      f16x2 hv = *(const f16x2*)&hs[(long)s * W + c0];
      a0 += a * (float)hv[0]; a1 += a * (float)hv[1];
    }
    float2 o = make_float2(a0 * inv, a1 * inv);
    *(float2*)&outp[(long)d * W + c0] = o;
  }
}

// ---------- BN zero ----------
__global__ void zero2_k(float* __restrict__ a, float* __restrict__ b) {
  int t = threadIdx.x;
  a[t] = 0.f; b[t] = 0.f;
}

// ---------- BN stats, both sides ----------
__global__ __launch_bounds__(256) void bn_stats2_k(const float* __restrict__ xu, float* __restrict__ su, int Nu, int gU,
                                                   const float* __restrict__ xi, float* __restrict__ si, int Ni) {
  const int C = 256;
  int b = blockIdx.x;
  const float* x; float* sums; int N; int r0;
  if (b < gU) { x = xu; sums = su; N = Nu; r0 = b * 64; }
  else        { x = xi; sums = si; N = Ni; r0 = (b - gU) * 64; }
  int c = threadIdx.x;
  int r1 = min(r0 + 64, N);
  float s = 0.f, s2 = 0.f;
  for (int r = r0; r < r1; ++r) {
    float v = x[(long)r * C + c];
    s += v; s2 += v * v;
  }
  atomicAdd(&sums[c], s);
  atomicAdd(&sums[C + c], s2);
}

// ---------- BN apply + activation -> f16, both sides ----------
__global__ void bn_apply2_k(const float* __restrict__ xu, const float* __restrict__ su,
                            const float* __restrict__ gbu, f16* __restrict__ yu, int Nu,
                            const float* __restrict__ xi, const float* __restrict__ si,
                            const float* __restrict__ gbi, f16* __restrict__ yi, int Ni,
                            int act) {
  const int C = 256;
  long idx = (long)blockIdx.x * blockDim.x + threadIdx.x;
  long nu = (long)Nu * C;
  const float* x; const float* sums; const float* gb; f16* y; long i; int N;
  if (idx < nu) { x = xu; sums = su; gb = gbu; y = yu; i = idx; N = Nu; }
  else if (idx < nu + (long)Ni * C) { x = xi; sums = si; gb = gbi; y = yi; i = idx - nu; N = Ni; }
  else return;
  int c = (int)(i & 255);
  float inv_n = 1.0f / (float)N;
  float mean = sums[c] * inv_n;
  float var = sums[C + c] * inv_n - mean * mean;
  float v = gb[c] * (x[i] - mean) * rsqrtf(var + 1e-5f) + gb[C + c];
  v = act ? tanhf(v) : (v > 0.f ? v : 0.01f * v);
  y[i] = (f16)v;
}

extern "C" void kernel_launch(void* const* d_in, const int* in_sizes, int n_in,
                              void* d_out, int out_size, void* d_ws, size_t ws_size,
                              hipStream_t stream) {
  const float* x_user = (const float*)d_in[0];
  const float* x_item = (const float*)d_in[1];
  const int* eu = (const int*)d_in[2];
  const int* ei = (const int*)d_in[3];
  const float *Wm[4][2], *Am[4][2];
  for (int L = 0; L < 4; ++L) {
    Wm[L][0] = (const float*)d_in[4 + L * 4 + 0];
    Am[L][0] = (const float*)d_in[4 + L * 4 + 1];
    Wm[L][1] = (const float*)d_in[4 + L * 4 + 2];
    Am[L][1] = (const float*)d_in[4 + L * 4 + 3];
  }
  const float* bnu = (const float*)d_in[20];
  const float* bni = (const float*)d_in[21];
  float* out = (float*)d_out;

  float* ws = (float*)d_ws;
  size_t o = 0;
  float* agg_u = ws + o; o += (size_t)NUSERS * 256;
  float* agg_i = ws + o; o += (size_t)NITEMS * 256;
  float* el_u = ws + o; o += (size_t)NUSERS * 4;
  float* er_u = ws + o; o += (size_t)NUSERS * 4;
  float* el_i = ws + o; o += (size_t)NITEMS * 4;
  float* er_i = ws + o; o += (size_t)NITEMS * 4;
  float* fold_ui = ws + o; o += 1024;
  float* fold_iu = ws + o; o += 1024;
  float* bns_u = ws + o; o += 512;
  float* bns_i = ws + o; o += 512;
  // f16 buffers (offsets in floats; all 16B aligned)
  f16* hb_u  = (f16*)(ws + o); o += (size_t)NUSERS * 128;
  f16* hb_i  = (f16*)(ws + o); o += (size_t)NITEMS * 128;
  f16* hsb_u = (f16*)(ws + o); o += (size_t)NUSERS * 128;
  f16* hsb_i = (f16*)(ws + o); o += (size_t)NITEMS * 128;
  f16* Bt_ui = (f16*)(ws + o); o += 32768;
  f16* Bt_iu = (f16*)(ws + o); o += 32768;
  // CSR scratch (deg_i/deg_u adjacent => single memset)
  int* deg_i    = (int*)(ws + o); o += NITEMS;
  int* deg_u    = (int*)(ws + o); o += NUSERS;
  int* rowptr_i = (int*)(ws + o); o += NITEMS + 1;
  int* rowptr_u = (int*)(ws + o); o += NUSERS + 1;
  int* cur_i    = (int*)(ws + o); o += NITEMS;
  int* cur_u    = (int*)(ws + o); o += NUSERS;
  int* bsum     = (int*)(ws + o); o += 256;
  int* csrsrc_i = (int*)(ws + o); o += NEDGES;
  int* csrsrc_u = (int*)(ws + o); o += NEDGES;

  const int gE2 = (2 * NEDGES + 255) / 256;
  const int nb_i = (NITEMS + 1023) / 1024;
  const int nb_u = (NUSERS + 1023) / 1024;
  const int gU = (NUSERS + 63) / 64;
  const int gI = (NITEMS + 63) / 64;

  // ---- CSR build (once; edges identical across layers) ----
  hipMemsetAsync(deg_i, 0, (NITEMS + NUSERS) * sizeof(int), stream);
  hist_k<<<dim3(gE2), dim3(256), 0, stream>>>(ei, deg_i, eu, deg_u);
  scan1_k<<<dim3(nb_i), dim3(256), 0, stream>>>(deg_i, bsum, NITEMS);
  scan2_k<<<dim3(1), dim3(64), 0, stream>>>(bsum, nb_i);
  scan3_k<<<dim3(nb_i), dim3(256), 0, stream>>>(deg_i, bsum, rowptr_i, NITEMS);
  setval_k<<<dim3(1), dim3(1), 0, stream>>>(rowptr_i + NITEMS, NEDGES);
  scan1_k<<<dim3(nb_u), dim3(256), 0, stream>>>(deg_u, bsum, NUSERS);
  scan2_k<<<dim3(1), dim3(64), 0, stream>>>(bsum, nb_u);
  scan3_k<<<dim3(nb_u), dim3(256), 0, stream>>>(deg_u, bsum, rowptr_u, NUSERS);
  setval_k<<<dim3(1), dim3(1), 0, stream>>>(rowptr_u + NUSERS, NEDGES);
  copy2_k<<<dim3((NITEMS + NUSERS + 255) / 256), dim3(256), 0, stream>>>(rowptr_i, cur_i, NITEMS, rowptr_u, cur_u, NUSERS);
  scat_k<<<dim3(gE2), dim3(256), 0, stream>>>(ei, eu, cur_i, csrsrc_i, cur_u, csrsrc_u);

  // layer-0 inputs -> f16
  xcvt_k<<<dim3(((NUSERS + NITEMS) * 128 + 255) / 256), dim3(256), 0, stream>>>(
      x_user, hb_u, (long)NUSERS * 128, x_item, hb_i, (long)NITEMS * 128);

  int K = 128;

  for (int L = 0; L < 4; ++L) {
    const int dh = (L == 3) ? 32 : 64;
    const int W = 4 * dh;
    const float* W_ui = Wm[L][0]; const float* A_ui = Am[L][0];
    const float* W_iu = Wm[L][1]; const float* A_iu = Am[L][1];

    prep_k<<<dim3((2 * K * W + 255) / 256), dim3(256), 0, stream>>>(
        W_ui, A_ui, Bt_ui, fold_ui, W_iu, A_iu, Bt_iu, fold_iu, K, W, dh);

    const int gya = (NUSERS + 127) / 128, gyb = (NITEMS + 127) / 128;
    hgemm2_k<<<dim3(W / 128, gya + gyb), dim3(256), 0, stream>>>(
        hb_u, Bt_ui, hsb_u, NUSERS, gya, hb_i, Bt_iu, hsb_i, NITEMS, W, K);

    eler2_k<<<dim3(NUSERS + NITEMS), dim3(256), 0, stream>>>(
        hsb_u, A_ui, hb_u, fold_iu, el_u, er_u,
        hsb_i, A_iu, hb_i, fold_ui, el_i, er_i, W, dh, K);

    float* dst_u; float* dst_i;
    if (L < 3) { dst_u = agg_u; dst_i = agg_i; }
    else { dst_u = out; dst_i = out + (size_t)NUSERS * 128; }

    agg_k<<<dim3((NITEMS + NUSERS + 3) / 4), dim3(256), 0, stream>>>(
        el_u, er_i, rowptr_i, csrsrc_i, hsb_u, dst_i, NITEMS,
        el_i, er_u, rowptr_u, csrsrc_u, hsb_i, dst_u, NUSERS, W, dh);

    if (L < 3) {
      zero2_k<<<dim3(1), dim3(512), 0, stream>>>(bns_u, bns_i);
      bn_stats2_k<<<dim3(gU + gI), dim3(256), 0, stream>>>(agg_u, bns_u, NUSERS, gU, agg_i, bns_i, NITEMS);
      bn_apply2_k<<<dim3((int)(((long)(NUSERS + NITEMS) * 256 + 255) / 256)), dim3(256), 0, stream>>>(
          agg_u, bns_u, bnu + L * 512, hb_u, NUSERS,
          agg_i, bns_i, bni + L * 512, hb_i, NITEMS, L == 2);
      K = 256;
    }
  }
}

// Round 6
// 1174.863 us; speedup vs baseline: 3.5199x; 1.1701x over previous
//
#include <hip/hip_runtime.h>

#define NUSERS 50000
#define NITEMS 20000
#define NEDGES 400000

typedef _Float16 f16;
typedef __attribute__((ext_vector_type(8))) _Float16 f16x8;
typedef __attribute__((ext_vector_type(4))) _Float16 f16x4;
typedef __attribute__((ext_vector_type(2))) _Float16 f16x2;
typedef __attribute__((ext_vector_type(4))) float f32x4;

// ---------- prep: weight transpose->f16 + folded el/er projections, both relations ----------
// Bt[n*K+k] = f16(W[k*Nw+n]);  ef[j*4K + h*K + f] = sum_d W[f*Nw + h*dh + d] * A[j][h][d], j=0(el),1(er)
__global__ void prep_k(const float* __restrict__ Wa, const float* __restrict__ Aa,
                       f16* __restrict__ Bta, float* __restrict__ efa,
                       const float* __restrict__ Wb, const float* __restrict__ Ab,
                       f16* __restrict__ Btb, float* __restrict__ efb,
                       int K, int Nw, int dh) {
  int t = blockIdx.x * blockDim.x + threadIdx.x;
  int half = K * Nw;
  if (t >= 2 * half) return;
  const float* W = (t < half) ? Wa : Wb;
  const float* A = (t < half) ? Aa : Ab;
  f16* Bt = (t < half) ? Bta : Btb;
  float* ef = (t < half) ? efa : efb;
  int t2 = (t < half) ? t : t - half;
  int n = t2 / K, k = t2 - n * K;
  Bt[t2] = (f16)W[(long)k * Nw + n];
  if (t2 < K * 8) {
    int j = t2 / (K * 4);
    int r = t2 - j * K * 4;
    int h = r / K, f = r - h * K;
    const float* Aj = A + j * Nw;   // A[j], shape [4,dh], Nw = 4*dh
    float s = 0.f;
    for (int d = 0; d < dh; ++d) s += W[f * Nw + h * dh + d] * Aj[h * dh + d];
    ef[j * 4 * K + h * K + f] = s;
  }
}

// ---------- fp32 -> f16 convert, both sides in one launch ----------
__global__ void xcvt_k(const float* __restrict__ xu, f16* __restrict__ yu, long nu,
                       const float* __restrict__ xi, f16* __restrict__ yi, long ni) {
  long i = (long)blockIdx.x * blockDim.x + threadIdx.x;
  if (i < nu) yu[i] = (f16)xu[i];
  else if (i < nu + ni) yi[i - nu] = (f16)xi[i - nu];
}

// ---------- f16 MFMA GEMM, user+item fused: C = A[M,K] @ Bt[N,K]^T ----------
__global__ __launch_bounds__(256) void hgemm2_k(const f16* __restrict__ Aa, const f16* __restrict__ Bta,
                                                f16* __restrict__ Ca, int Ma, int gya,
                                                const f16* __restrict__ Ab, const f16* __restrict__ Btb,
                                                f16* __restrict__ Cb, int Mb,
                                                int N, int K) {
  __shared__ f16 As[128 * 32];
  __shared__ f16 Bs[128 * 32];
  int by = blockIdx.y;
  const f16* A; const f16* Bt; f16* C; int M; int row0;
  if (by < gya) { A = Aa; Bt = Bta; C = Ca; M = Ma; row0 = by * 128; }
  else          { A = Ab; Bt = Btb; C = Cb; M = Mb; row0 = (by - gya) * 128; }
  int tid = threadIdx.x;
  int col0 = blockIdx.x * 128;
  int lane = tid & 63, wv = tid >> 6;
  int wr = (wv & 1) * 64, wc = (wv >> 1) * 64;
  int l16 = lane & 15, q = lane >> 4;
  f32x4 acc[4][4] = {};
  int r = tid >> 2, c8 = (tid & 3) * 8;
  for (int k0 = 0; k0 < K; k0 += 32) {
    int ra = min(row0 + r, M - 1);
    uint4 va = *(const uint4*)&A[(long)ra * K + k0 + c8];
    int ra2 = min(row0 + r + 64, M - 1);
    uint4 va2 = *(const uint4*)&A[(long)ra2 * K + k0 + c8];
    uint4 vb = *(const uint4*)&Bt[(long)(col0 + r) * K + k0 + c8];
    uint4 vb2 = *(const uint4*)&Bt[(long)(col0 + r + 64) * K + k0 + c8];
    *(uint4*)&As[r * 32 + c8] = va;
    *(uint4*)&As[(r + 64) * 32 + c8] = va2;
    *(uint4*)&Bs[r * 32 + c8] = vb;
    *(uint4*)&Bs[(r + 64) * 32 + c8] = vb2;
    __syncthreads();
    f16x8 af[4], bfr[4];
#pragma unroll
    for (int i = 0; i < 4; ++i) {
      af[i] = *(const f16x8*)&As[(wr + i * 16 + l16) * 32 + q * 8];
      bfr[i] = *(const f16x8*)&Bs[(wc + i * 16 + l16) * 32 + q * 8];
    }
#pragma unroll
    for (int i = 0; i < 4; ++i)
#pragma unroll
      for (int j = 0; j < 4; ++j)
        acc[i][j] = __builtin_amdgcn_mfma_f32_16x16x32_f16(af[i], bfr[j], acc[i][j], 0, 0, 0);
    __syncthreads();
  }
#pragma unroll
  for (int i = 0; i < 4; ++i) {
#pragma unroll
    for (int reg = 0; reg < 4; ++reg) {
      int rr = row0 + wr + i * 16 + q * 4 + reg;
      if (rr < M) {
#pragma unroll
        for (int j = 0; j < 4; ++j)
          C[(long)rr * N + col0 + wc + j * 16 + l16] = (f16)acc[i][j][reg];
      }
    }
  }
}

// ---------- el+er via folds; reads only hb (K f16 per node); block per node ----------
__global__ __launch_bounds__(256) void eler_k(
    const f16* __restrict__ hbu, const float* __restrict__ ef_ui, const float* __restrict__ ef_iu,
    float* __restrict__ el_u, float* __restrict__ er_u,
    const f16* __restrict__ hbi, float* __restrict__ el_i, float* __restrict__ er_i, int K) {
  __shared__ float xs[256];
  int b = blockIdx.x, t = threadIdx.x;
  const f16* hb; const float* elf; const float* erf; float* el; float* er; int n;
  if (b < NUSERS) { hb = hbu; elf = ef_ui; erf = ef_iu + 4 * K; el = el_u; er = er_u; n = b; }
  else            { hb = hbi; elf = ef_iu; erf = ef_ui + 4 * K; el = el_i; er = er_i; n = b - NUSERS; }
  if (t < K) xs[t] = (float)hb[(long)n * K + t];
  __syncthreads();
  int j = t >> 5, l = t & 31;                 // 8 dot-products x 32 lanes
  const float* fr = (j < 4) ? (elf + j * K) : (erf + (j - 4) * K);
  float p = 0.f;
  for (int f = l; f < K; f += 32) p += xs[f] * fr[f];
#pragma unroll
  for (int off = 16; off; off >>= 1) p += __shfl_down(p, off, 32);
  if (l == 0) { if (j < 4) el[n * 4 + j] = p; else er[n * 4 + (j - 4)] = p; }
}

// ---------- CSR build ----------
__global__ void hist_k(const int* __restrict__ ei, int* __restrict__ degi,
                       const int* __restrict__ eu, int* __restrict__ degu) {
  int e = blockIdx.x * blockDim.x + threadIdx.x;
  if (e < NEDGES) atomicAdd(&degi[ei[e]], 1);
  else if (e < 2 * NEDGES) atomicAdd(&degu[eu[e - NEDGES]], 1);
}

__global__ __launch_bounds__(256) void scan1_k(const int* __restrict__ deg,
                                               int* __restrict__ bsum, int N) {
  __shared__ int red[256];
  int base = blockIdx.x * 1024, t = threadIdx.x;
  int s = 0;
#pragma unroll
  for (int j = 0; j < 4; ++j) { int i = base + t * 4 + j; s += (i < N) ? deg[i] : 0; }
  red[t] = s; __syncthreads();
  for (int off = 128; off; off >>= 1) { if (t < off) red[t] += red[t + off]; __syncthreads(); }
  if (t == 0) bsum[blockIdx.x] = red[0];
}

__global__ void scan2_k(int* __restrict__ bsum, int nb) {
  if (threadIdx.x == 0) {
    int run = 0;
    for (int i = 0; i < nb; ++i) { int v = bsum[i]; bsum[i] = run; run += v; }
  }
}

__global__ __launch_bounds__(256) void scan3_k(const int* __restrict__ deg,
                                               const int* __restrict__ bsum,
                                               int* __restrict__ rowptr, int N) {
  __shared__ int tsum[256];
  int base = blockIdx.x * 1024, t = threadIdx.x;
  int v[4]; int s = 0;
#pragma unroll
  for (int j = 0; j < 4; ++j) { int i = base + t * 4 + j; v[j] = (i < N) ? deg[i] : 0; s += v[j]; }
  tsum[t] = s; __syncthreads();
  for (int off = 1; off < 256; off <<= 1) {
    int x = (t >= off) ? tsum[t - off] : 0;
    __syncthreads();
    tsum[t] += x;
    __syncthreads();
  }
  int run = bsum[blockIdx.x] + ((t > 0) ? tsum[t - 1] : 0);
#pragma unroll
  for (int j = 0; j < 4; ++j) {
    int i = base + t * 4 + j;
    if (i < N) rowptr[i] = run;
    run += v[j];
  }
}

__global__ void setval_k(int* __restrict__ p, int v) { *p = v; }

__global__ void copy2_k(const int* __restrict__ a, int* __restrict__ b, int Na,
                        const int* __restrict__ c, int* __restrict__ d, int Nc) {
  int i = blockIdx.x * blockDim.x + threadIdx.x;
  if (i < Na) b[i] = a[i];
  else if (i < Na + Nc) d[i - Na] = c[i - Na];
}

__global__ void scat_k(const int* __restrict__ ei, const int* __restrict__ eu,
                       int* __restrict__ curi, int* __restrict__ srci,
                       int* __restrict__ curu, int* __restrict__ srcu) {
  int e = blockIdx.x * blockDim.x + threadIdx.x;
  if (e < NEDGES) {
    int p = atomicAdd(&curi[ei[e]], 1);
    srci[p] = eu[e];
  } else if (e < 2 * NEDGES) {
    int e2 = e - NEDGES;
    int p = atomicAdd(&curu[eu[e2]], 1);
    srcu[p] = ei[e2];
  }
}

// ---------- fused segment-softmax + gather; wave per dst ----------
// alpha staged per-wave in LDS as float4(e0..e3) per edge; reader selects ITS OWN head.
template <int W, int DH>
__global__ __launch_bounds__(256) void agg_k(
    const float* __restrict__ elA, const float* __restrict__ erA,
    const int* __restrict__ rpA, const int* __restrict__ srcA,
    const f16* __restrict__ hsA, float* __restrict__ outA, int nA,
    const float* __restrict__ elB, const float* __restrict__ erB,
    const int* __restrict__ rpB, const int* __restrict__ srcB,
    const f16* __restrict__ hsB, float* __restrict__ outB, int nB) {
  constexpr int CPL = W >> 6;   // channels per lane
  __shared__ float alds[4][256];   // [wave][edge*4 + head]
  int wv = threadIdx.x >> 6;
  int g = blockIdx.x * 4 + wv;
  int lane = threadIdx.x & 63;
  const float* el; const float* er; const int* rp; const int* srcv;
  const f16* hs; float* outp; int d;
  if (g < nA)           { el = elA; er = erA; rp = rpA; srcv = srcA; hs = hsA; outp = outA; d = g; }
  else if (g < nA + nB) { el = elB; er = erB; rp = rpB; srcv = srcB; hs = hsB; outp = outB; d = g - nA; }
  else return;
  int s0 = rp[d], s1 = rp[d + 1];
  int deg = s1 - s0;
  int c0 = lane * CPL;
  int h = c0 / DH;
  long obase = (long)d * W + c0;
  if (deg == 0) {
#pragma unroll
    for (int q = 0; q < CPL; ++q) outp[obase + q] = 0.f;
    return;
  }
  float4 er4 = *(const float4*)&er[d * 4];
  const float NEG = -3.0e38f;
  float acc[CPL];
#pragma unroll
  for (int q = 0; q < CPL; ++q) acc[q] = 0.f;
  float inv;

  if (deg <= 64) {
    // ---- register-resident logits: load once, reduce, stage exp in LDS ----
    int k = s0 + lane;
    int sreg = 0;
    float v0 = NEG, v1 = NEG, v2 = NEG, v3 = NEG;
    if (k < s1) {
      sreg = srcv[k];
      float4 e4 = *(const float4*)&el[sreg * 4];
      v0 = e4.x + er4.x; v0 = v0 > 0.f ? v0 : 0.2f * v0;
      v1 = e4.y + er4.y; v1 = v1 > 0.f ? v1 : 0.2f * v1;
      v2 = e4.z + er4.z; v2 = v2 > 0.f ? v2 : 0.2f * v2;
      v3 = e4.w + er4.w; v3 = v3 > 0.f ? v3 : 0.2f * v3;
    }
    float m0 = v0, m1 = v1, m2 = v2, m3 = v3;
#pragma unroll
    for (int off = 32; off; off >>= 1) {
      m0 = fmaxf(m0, __shfl_xor(m0, off, 64));
      m1 = fmaxf(m1, __shfl_xor(m1, off, 64));
      m2 = fmaxf(m2, __shfl_xor(m2, off, 64));
      m3 = fmaxf(m3, __shfl_xor(m3, off, 64));
    }
    float e0 = 0.f, e1 = 0.f, e2 = 0.f, e3 = 0.f;
    if (k < s1) {
      e0 = expf(v0 - m0); e1 = expf(v1 - m1);
      e2 = expf(v2 - m2); e3 = expf(v3 - m3);
    }
    // stage all 4 heads' exp for this lane's edge; readers pick their own head
    *(float4*)&alds[wv][lane * 4] = make_float4(e0, e1, e2, e3);
    float S0 = e0, S1 = e1, S2 = e2, S3 = e3;
#pragma unroll
    for (int off = 32; off; off >>= 1) {
      S0 += __shfl_xor(S0, off, 64);
      S1 += __shfl_xor(S1, off, 64);
      S2 += __shfl_xor(S2, off, 64);
      S3 += __shfl_xor(S3, off, 64);
    }
    float Sh = h == 0 ? S0 : h == 1 ? S1 : h == 2 ? S2 : S3;
    inv = 1.0f / Sh;
    // ---- gather: alpha from LDS (own head), src by shuffle, no expf ----
    for (int j = 0; j < deg; ++j) {
      float aj = alds[wv][j * 4 + h];
      int sj = __shfl(sreg, j, 64);
      const f16* row = &hs[(long)sj * W + c0];
      if constexpr (CPL == 4) {
        f16x4 hv = *(const f16x4*)row;
        acc[0] += aj * (float)hv[0]; acc[1] += aj * (float)hv[1];
        acc[2] += aj * (float)hv[2]; acc[3] += aj * (float)hv[3];
      } else {
        f16x2 hv = *(const f16x2*)row;
        acc[0] += aj * (float)hv[0]; acc[1] += aj * (float)hv[1];
      }
    }
  } else {
    // ---- generic fallback (deg > 64): strided two-pass + serial gather ----
    float m0 = NEG, m1 = NEG, m2 = NEG, m3 = NEG;
    for (int k = s0 + lane; k < s1; k += 64) {
      int s = srcv[k];
      float4 e4 = *(const float4*)&el[s * 4];
      float v;
      v = e4.x + er4.x; v = v > 0.f ? v : 0.2f * v; m0 = fmaxf(m0, v);
      v = e4.y + er4.y; v = v > 0.f ? v : 0.2f * v; m1 = fmaxf(m1, v);
      v = e4.z + er4.z; v = v > 0.f ? v : 0.2f * v; m2 = fmaxf(m2, v);
      v = e4.w + er4.w; v = v > 0.f ? v : 0.2f * v; m3 = fmaxf(m3, v);
    }
#pragma unroll
    for (int off = 32; off; off >>= 1) {
      m0 = fmaxf(m0, __shfl_xor(m0, off, 64));
      m1 = fmaxf(m1, __shfl_xor(m1, off, 64));
      m2 = fmaxf(m2, __shfl_xor(m2, off, 64));
      m3 = fmaxf(m3, __shfl_xor(m3, off, 64));
    }
    float S0 = 0.f, S1 = 0.f, S2 = 0.f, S3 = 0.f;
    for (int k = s0 + lane; k < s1; k += 64) {
      int s = srcv[k];
      float4 e4 = *(const float4*)&el[s * 4];
      float v;
      v = e4.x + er4.x; v = v > 0.f ? v : 0.2f * v; S0 += expf(v - m0);
      v = e4.y + er4.y; v = v > 0.f ? v : 0.2f * v; S1 += expf(v - m1);
      v = e4.z + er4.z; v = v > 0.f ? v : 0.2f * v; S2 += expf(v - m2);
      v = e4.w + er4.w; v = v > 0.f ? v : 0.2f * v; S3 += expf(v - m3);
    }
#pragma unroll
    for (int off = 32; off; off >>= 1) {
      S0 += __shfl_xor(S0, off, 64);
      S1 += __shfl_xor(S1, off, 64);
      S2 += __shfl_xor(S2, off, 64);
      S3 += __shfl_xor(S3, off, 64);
    }
    float mh = h == 0 ? m0 : h == 1 ? m1 : h == 2 ? m2 : m3;
    float Sh = h == 0 ? S0 : h == 1 ? S1 : h == 2 ? S2 : S3;
    float erh = h == 0 ? er4.x : h == 1 ? er4.y : h == 2 ? er4.z : er4.w;
    inv = 1.0f / Sh;
    for (int k = s0; k < s1; ++k) {
      int s = srcv[k];
      float v = el[s * 4 + h] + erh; v = v > 0.f ? v : 0.2f * v;
      float a = expf(v - mh);
      const f16* row = &hs[(long)s * W + c0];
      if constexpr (CPL == 4) {
        f16x4 hv = *(const f16x4*)row;
        acc[0] += a * (float)hv[0]; acc[1] += a * (float)hv[1];
        acc[2] += a * (float)hv[2]; acc[3] += a * (float)hv[3];
      } else {
        f16x2 hv = *(const f16x2*)row;
        acc[0] += a * (float)hv[0]; acc[1] += a * (float)hv[1];
      }
    }
  }
  if constexpr (CPL == 4) {
    *(float4*)&outp[obase] = make_float4(acc[0] * inv, acc[1] * inv, acc[2] * inv, acc[3] * inv);
  } else {
    *(float2*)&outp[obase] = make_float2(acc[0] * inv, acc[1] * inv);
  }
}

// ---------- BN zero ----------
__global__ void zero2_k(float* __restrict__ a, float* __restrict__ b) {
  int t = threadIdx.x;
  a[t] = 0.f; b[t] = 0.f;
}

// ---------- BN stats, both sides ----------
__global__ __launch_bounds__(256) void bn_stats2_k(const float* __restrict__ xu, float* __restrict__ su, int Nu, int gU,
                                                   const float* __restrict__ xi, float* __restrict__ si, int Ni) {
  const int C = 256;
  int b = blockIdx.x;
  const float* x; float* sums; int N; int r0;
  if (b < gU) { x = xu; sums = su; N = Nu; r0 = b * 64; }
  else        { x = xi; sums = si; N = Ni; r0 = (b - gU) * 64; }
  int c = threadIdx.x;
  int r1 = min(r0 + 64, N);
  float s = 0.f, s2 = 0.f;
  for (int r = r0; r < r1; ++r) {
    float v = x[(long)r * C + c];
    s += v; s2 += v * v;
  }
  atomicAdd(&sums[c], s);
  atomicAdd(&sums[C + c], s2);
}

// ---------- BN apply + activation -> f16, both sides ----------
__global__ void bn_apply2_k(const float* __restrict__ xu, const float* __restrict__ su,
                            const float* __restrict__ gbu, f16* __restrict__ yu, int Nu,
                            const float* __restrict__ xi, const float* __restrict__ si,
                            const float* __restrict__ gbi, f16* __restrict__ yi, int Ni,
                            int act) {
  const int C = 256;
  long idx = (long)blockIdx.x * blockDim.x + threadIdx.x;
  long nu = (long)Nu * C;
  const float* x; const float* sums; const float* gb; f16* y; long i; int N;
  if (idx < nu) { x = xu; sums = su; gb = gbu; y = yu; i = idx; N = Nu; }
  else if (idx < nu + (long)Ni * C) { x = xi; sums = si; gb = gbi; y = yi; i = idx - nu; N = Ni; }
  else return;
  int c = (int)(i & 255);
  float inv_n = 1.0f / (float)N;
  float mean = sums[c] * inv_n;
  float var = sums[C + c] * inv_n - mean * mean;
  float v = gb[c] * (x[i] - mean) * rsqrtf(var + 1e-5f) + gb[C + c];
  v = act ? tanhf(v) : (v > 0.f ? v : 0.01f * v);
  y[i] = (f16)v;
}

extern "C" void kernel_launch(void* const* d_in, const int* in_sizes, int n_in,
                              void* d_out, int out_size, void* d_ws, size_t ws_size,
                              hipStream_t stream) {
  const float* x_user = (const float*)d_in[0];
  const float* x_item = (const float*)d_in[1];
  const int* eu = (const int*)d_in[2];
  const int* ei = (const int*)d_in[3];
  const float *Wm[4][2], *Am[4][2];
  for (int L = 0; L < 4; ++L) {
    Wm[L][0] = (const float*)d_in[4 + L * 4 + 0];
    Am[L][0] = (const float*)d_in[4 + L * 4 + 1];
    Wm[L][1] = (const float*)d_in[4 + L * 4 + 2];
    Am[L][1] = (const float*)d_in[4 + L * 4 + 3];
  }
  const float* bnu = (const float*)d_in[20];
  const float* bni = (const float*)d_in[21];
  float* out = (float*)d_out;

  float* ws = (float*)d_ws;
  size_t o = 0;
  float* agg_u = ws + o; o += (size_t)NUSERS * 256;
  float* agg_i = ws + o; o += (size_t)NITEMS * 256;
  float* el_u = ws + o; o += (size_t)NUSERS * 4;
  float* er_u = ws + o; o += (size_t)NUSERS * 4;
  float* el_i = ws + o; o += (size_t)NITEMS * 4;
  float* er_i = ws + o; o += (size_t)NITEMS * 4;
  float* ef_ui = ws + o; o += 2048;   // [2][4][K<=256] el/er folds
  float* ef_iu = ws + o; o += 2048;
  float* bns_u = ws + o; o += 512;
  float* bns_i = ws + o; o += 512;
  // f16 buffers (offsets in floats; all 16B aligned)
  f16* hb_u  = (f16*)(ws + o); o += (size_t)NUSERS * 128;
  f16* hb_i  = (f16*)(ws + o); o += (size_t)NITEMS * 128;
  f16* hsb_u = (f16*)(ws + o); o += (size_t)NUSERS * 128;
  f16* hsb_i = (f16*)(ws + o); o += (size_t)NITEMS * 128;
  f16* Bt_ui = (f16*)(ws + o); o += 32768;
  f16* Bt_iu = (f16*)(ws + o); o += 32768;
  // CSR scratch (deg_i/deg_u adjacent => single memset)
  int* deg_i    = (int*)(ws + o); o += NITEMS;
  int* deg_u    = (int*)(ws + o); o += NUSERS;
  int* rowptr_i = (int*)(ws + o); o += NITEMS + 1;
  int* rowptr_u = (int*)(ws + o); o += NUSERS + 1;
  int* cur_i    = (int*)(ws + o); o += NITEMS;
  int* cur_u    = (int*)(ws + o); o += NUSERS;
  int* bsum     = (int*)(ws + o); o += 256;
  int* csrsrc_i = (int*)(ws + o); o += NEDGES;
  int* csrsrc_u = (int*)(ws + o); o += NEDGES;

  const int gE2 = (2 * NEDGES + 255) / 256;
  const int nb_i = (NITEMS + 1023) / 1024;
  const int nb_u = (NUSERS + 1023) / 1024;
  const int gU = (NUSERS + 63) / 64;
  const int gI = (NITEMS + 63) / 64;

  // ---- CSR build (once; edges identical across layers) ----
  hipMemsetAsync(deg_i, 0, (NITEMS + NUSERS) * sizeof(int), stream);
  hist_k<<<dim3(gE2), dim3(256), 0, stream>>>(ei, deg_i, eu, deg_u);
  scan1_k<<<dim3(nb_i), dim3(256), 0, stream>>>(deg_i, bsum, NITEMS);
  scan2_k<<<dim3(1), dim3(64), 0, stream>>>(bsum, nb_i);
  scan3_k<<<dim3(nb_i), dim3(256), 0, stream>>>(deg_i, bsum, rowptr_i, NITEMS);
  setval_k<<<dim3(1), dim3(1), 0, stream>>>(rowptr_i + NITEMS, NEDGES);
  scan1_k<<<dim3(nb_u), dim3(256), 0, stream>>>(deg_u, bsum, NUSERS);
  scan2_k<<<dim3(1), dim3(64), 0, stream>>>(bsum, nb_u);
  scan3_k<<<dim3(nb_u), dim3(256), 0, stream>>>(deg_u, bsum, rowptr_u, NUSERS);
  setval_k<<<dim3(1), dim3(1), 0, stream>>>(rowptr_u + NUSERS, NEDGES);
  copy2_k<<<dim3((NITEMS + NUSERS + 255) / 256), dim3(256), 0, stream>>>(rowptr_i, cur_i, NITEMS, rowptr_u, cur_u, NUSERS);
  scat_k<<<dim3(gE2), dim3(256), 0, stream>>>(ei, eu, cur_i, csrsrc_i, cur_u, csrsrc_u);

  // layer-0 inputs -> f16
  xcvt_k<<<dim3(((NUSERS + NITEMS) * 128 + 255) / 256), dim3(256), 0, stream>>>(
      x_user, hb_u, (long)NUSERS * 128, x_item, hb_i, (long)NITEMS * 128);

  int K = 128;

  for (int L = 0; L < 4; ++L) {
    const int dh = (L == 3) ? 32 : 64;
    const int W = 4 * dh;
    const float* W_ui = Wm[L][0]; const float* A_ui = Am[L][0];
    const float* W_iu = Wm[L][1]; const float* A_iu = Am[L][1];

    prep_k<<<dim3((2 * K * W + 255) / 256), dim3(256), 0, stream>>>(
        W_ui, A_ui, Bt_ui, ef_ui, W_iu, A_iu, Bt_iu, ef_iu, K, W, dh);

    const int gya = (NUSERS + 127) / 128, gyb = (NITEMS + 127) / 128;
    hgemm2_k<<<dim3(W / 128, gya + gyb), dim3(256), 0, stream>>>(
        hb_u, Bt_ui, hsb_u, NUSERS, gya, hb_i, Bt_iu, hsb_i, NITEMS, W, K);

    eler_k<<<dim3(NUSERS + NITEMS), dim3(256), 0, stream>>>(
        hb_u, ef_ui, ef_iu, el_u, er_u, hb_i, el_i, er_i, K);

    float* dst_u; float* dst_i;
    if (L < 3) { dst_u = agg_u; dst_i = agg_i; }
    else { dst_u = out; dst_i = out + (size_t)NUSERS * 128; }

    const int gAgg = (NITEMS + NUSERS + 3) / 4;
    if (L < 3)
      agg_k<256, 64><<<dim3(gAgg), dim3(256), 0, stream>>>(
          el_u, er_i, rowptr_i, csrsrc_i, hsb_u, dst_i, NITEMS,
          el_i, er_u, rowptr_u, csrsrc_u, hsb_i, dst_u, NUSERS);
    else
      agg_k<128, 32><<<dim3(gAgg), dim3(256), 0, stream>>>(
          el_u, er_i, rowptr_i, csrsrc_i, hsb_u, dst_i, NITEMS,
          el_i, er_u, rowptr_u, csrsrc_u, hsb_i, dst_u, NUSERS);

    if (L < 3) {
      zero2_k<<<dim3(1), dim3(512), 0, stream>>>(bns_u, bns_i);
      bn_stats2_k<<<dim3(gU + gI), dim3(256), 0, stream>>>(agg_u, bns_u, NUSERS, gU, agg_i, bns_i, NITEMS);
      bn_apply2_k<<<dim3((int)(((long)(NUSERS + NITEMS) * 256 + 255) / 256)), dim3(256), 0, stream>>>(
          agg_u, bns_u, bnu + L * 512, hb_u, NUSERS,
          agg_i, bns_i, bni + L * 512, hb_i, NITEMS, L == 2);
      K = 256;
    }
  }
}

// Round 7
// 996.537 us; speedup vs baseline: 4.1498x; 1.1789x over previous
//
#include <hip/hip_runtime.h>

#define NUSERS 50000
#define NITEMS 20000
#define NEDGES 400000

typedef _Float16 f16;
typedef __attribute__((ext_vector_type(8))) _Float16 f16x8;
typedef __attribute__((ext_vector_type(4))) _Float16 f16x4;
typedef __attribute__((ext_vector_type(2))) _Float16 f16x2;
typedef __attribute__((ext_vector_type(4))) float f32x4;

// ---------- prep: weight transpose->f16 + folded el/er projections, both relations ----------
__global__ void prep_k(const float* __restrict__ Wa, const float* __restrict__ Aa,
                       f16* __restrict__ Bta, float* __restrict__ efa,
                       const float* __restrict__ Wb, const float* __restrict__ Ab,
                       f16* __restrict__ Btb, float* __restrict__ efb,
                       int K, int Nw, int dh) {
  int t = blockIdx.x * blockDim.x + threadIdx.x;
  int half = K * Nw;
  if (t >= 2 * half) return;
  const float* W = (t < half) ? Wa : Wb;
  const float* A = (t < half) ? Aa : Ab;
  f16* Bt = (t < half) ? Bta : Btb;
  float* ef = (t < half) ? efa : efb;
  int t2 = (t < half) ? t : t - half;
  int n = t2 / K, k = t2 - n * K;
  Bt[t2] = (f16)W[(long)k * Nw + n];
  if (t2 < K * 8) {
    int j = t2 / (K * 4);
    int r = t2 - j * K * 4;
    int h = r / K, f = r - h * K;
    const float* Aj = A + j * Nw;   // A[j], shape [4,dh], Nw = 4*dh
    float s = 0.f;
    for (int d = 0; d < dh; ++d) s += W[f * Nw + h * dh + d] * Aj[h * dh + d];
    ef[j * 4 * K + h * K + f] = s;
  }
}

// ---------- fp32 -> f16 convert, both sides in one launch ----------
__global__ void xcvt_k(const float* __restrict__ xu, f16* __restrict__ yu, long nu,
                       const float* __restrict__ xi, f16* __restrict__ yi, long ni) {
  long i = (long)blockIdx.x * blockDim.x + threadIdx.x;
  if (i < nu) yu[i] = (f16)xu[i];
  else if (i < nu + ni) yi[i - nu] = (f16)xi[i - nu];
}

// ---------- f16 MFMA GEMM, user+item fused: C = A[M,K] @ Bt[N,K]^T ----------
__global__ __launch_bounds__(256) void hgemm2_k(const f16* __restrict__ Aa, const f16* __restrict__ Bta,
                                                f16* __restrict__ Ca, int Ma, int gya,
                                                const f16* __restrict__ Ab, const f16* __restrict__ Btb,
                                                f16* __restrict__ Cb, int Mb,
                                                int N, int K) {
  __shared__ f16 As[128 * 32];
  __shared__ f16 Bs[128 * 32];
  int by = blockIdx.y;
  const f16* A; const f16* Bt; f16* C; int M; int row0;
  if (by < gya) { A = Aa; Bt = Bta; C = Ca; M = Ma; row0 = by * 128; }
  else          { A = Ab; Bt = Btb; C = Cb; M = Mb; row0 = (by - gya) * 128; }
  int tid = threadIdx.x;
  int col0 = blockIdx.x * 128;
  int lane = tid & 63, wv = tid >> 6;
  int wr = (wv & 1) * 64, wc = (wv >> 1) * 64;
  int l16 = lane & 15, q = lane >> 4;
  f32x4 acc[4][4] = {};
  int r = tid >> 2, c8 = (tid & 3) * 8;
  for (int k0 = 0; k0 < K; k0 += 32) {
    int ra = min(row0 + r, M - 1);
    uint4 va = *(const uint4*)&A[(long)ra * K + k0 + c8];
    int ra2 = min(row0 + r + 64, M - 1);
    uint4 va2 = *(const uint4*)&A[(long)ra2 * K + k0 + c8];
    uint4 vb = *(const uint4*)&Bt[(long)(col0 + r) * K + k0 + c8];
    uint4 vb2 = *(const uint4*)&Bt[(long)(col0 + r + 64) * K + k0 + c8];
    *(uint4*)&As[r * 32 + c8] = va;
    *(uint4*)&As[(r + 64) * 32 + c8] = va2;
    *(uint4*)&Bs[r * 32 + c8] = vb;
    *(uint4*)&Bs[(r + 64) * 32 + c8] = vb2;
    __syncthreads();
    f16x8 af[4], bfr[4];
#pragma unroll
    for (int i = 0; i < 4; ++i) {
      af[i] = *(const f16x8*)&As[(wr + i * 16 + l16) * 32 + q * 8];
      bfr[i] = *(const f16x8*)&Bs[(wc + i * 16 + l16) * 32 + q * 8];
    }
#pragma unroll
    for (int i = 0; i < 4; ++i)
#pragma unroll
      for (int j = 0; j < 4; ++j)
        acc[i][j] = __builtin_amdgcn_mfma_f32_16x16x32_f16(af[i], bfr[j], acc[i][j], 0, 0, 0);
    __syncthreads();
  }
#pragma unroll
  for (int i = 0; i < 4; ++i) {
#pragma unroll
    for (int reg = 0; reg < 4; ++reg) {
      int rr = row0 + wr + i * 16 + q * 4 + reg;
      if (rr < M) {
#pragma unroll
        for (int j = 0; j < 4; ++j)
          C[(long)rr * N + col0 + wc + j * 16 + l16] = (f16)acc[i][j][reg];
      }
    }
  }
}

// ---------- el+er via folds (layer 0 only); block per node ----------
__global__ __launch_bounds__(256) void eler_k(
    const f16* __restrict__ hbu, const float* __restrict__ ef_ui, const float* __restrict__ ef_iu,
    float* __restrict__ el_u, float* __restrict__ er_u,
    const f16* __restrict__ hbi, float* __restrict__ el_i, float* __restrict__ er_i, int K) {
  __shared__ float xs[256];
  int b = blockIdx.x, t = threadIdx.x;
  const f16* hb; const float* elf; const float* erf; float* el; float* er; int n;
  if (b < NUSERS) { hb = hbu; elf = ef_ui; erf = ef_iu + 4 * K; el = el_u; er = er_u; n = b; }
  else            { hb = hbi; elf = ef_iu; erf = ef_ui + 4 * K; el = el_i; er = er_i; n = b - NUSERS; }
  if (t < K) xs[t] = (float)hb[(long)n * K + t];
  __syncthreads();
  int j = t >> 5, l = t & 31;
  const float* fr = (j < 4) ? (elf + j * K) : (erf + (j - 4) * K);
  float p = 0.f;
  for (int f = l; f < K; f += 32) p += xs[f] * fr[f];
#pragma unroll
  for (int off = 16; off; off >>= 1) p += __shfl_down(p, off, 32);
  if (l == 0) { if (j < 4) el[n * 4 + j] = p; else er[n * 4 + (j - 4)] = p; }
}

// ---------- CSR build ----------
__global__ void hist_k(const int* __restrict__ ei, int* __restrict__ degi,
                       const int* __restrict__ eu, int* __restrict__ degu) {
  int e = blockIdx.x * blockDim.x + threadIdx.x;
  if (e < NEDGES) atomicAdd(&degi[ei[e]], 1);
  else if (e < 2 * NEDGES) atomicAdd(&degu[eu[e - NEDGES]], 1);
}

__global__ __launch_bounds__(256) void scan1_k(const int* __restrict__ deg,
                                               int* __restrict__ bsum, int N) {
  __shared__ int red[256];
  int base = blockIdx.x * 1024, t = threadIdx.x;
  int s = 0;
#pragma unroll
  for (int j = 0; j < 4; ++j) { int i = base + t * 4 + j; s += (i < N) ? deg[i] : 0; }
  red[t] = s; __syncthreads();
  for (int off = 128; off; off >>= 1) { if (t < off) red[t] += red[t + off]; __syncthreads(); }
  if (t == 0) bsum[blockIdx.x] = red[0];
}

__global__ void scan2_k(int* __restrict__ bsum, int nb) {
  if (threadIdx.x == 0) {
    int run = 0;
    for (int i = 0; i < nb; ++i) { int v = bsum[i]; bsum[i] = run; run += v; }
  }
}

__global__ __launch_bounds__(256) void scan3_k(const int* __restrict__ deg,
                                               const int* __restrict__ bsum,
                                               int* __restrict__ rowptr, int N) {
  __shared__ int tsum[256];
  int base = blockIdx.x * 1024, t = threadIdx.x;
  int v[4]; int s = 0;
#pragma unroll
  for (int j = 0; j < 4; ++j) { int i = base + t * 4 + j; v[j] = (i < N) ? deg[i] : 0; s += v[j]; }
  tsum[t] = s; __syncthreads();
  for (int off = 1; off < 256; off <<= 1) {
    int x = (t >= off) ? tsum[t - off] : 0;
    __syncthreads();
    tsum[t] += x;
    __syncthreads();
  }
  int run = bsum[blockIdx.x] + ((t > 0) ? tsum[t - 1] : 0);
#pragma unroll
  for (int j = 0; j < 4; ++j) {
    int i = base + t * 4 + j;
    if (i < N) rowptr[i] = run;
    run += v[j];
  }
}

__global__ void setval_k(int* __restrict__ p, int v) { *p = v; }

__global__ void copy2_k(const int* __restrict__ a, int* __restrict__ b, int Na,
                        const int* __restrict__ c, int* __restrict__ d, int Nc) {
  int i = blockIdx.x * blockDim.x + threadIdx.x;
  if (i < Na) b[i] = a[i];
  else if (i < Na + Nc) d[i - Na] = c[i - Na];
}

__global__ void scat_k(const int* __restrict__ ei, const int* __restrict__ eu,
                       int* __restrict__ curi, int* __restrict__ srci,
                       int* __restrict__ curu, int* __restrict__ srcu) {
  int e = blockIdx.x * blockDim.x + threadIdx.x;
  if (e < NEDGES) {
    int p = atomicAdd(&curi[ei[e]], 1);
    srci[p] = eu[e];
  } else if (e < 2 * NEDGES) {
    int e2 = e - NEDGES;
    int p = atomicAdd(&curu[eu[e2]], 1);
    srcu[p] = ei[e2];
  }
}

// ---------- fused segment-softmax + gather; wave per dst; OUT = f16 (hidden) or float (final) ----------
template <int W, int DH, typename OUT>
__global__ __launch_bounds__(256) void agg_k(
    const float* __restrict__ elA, const float* __restrict__ erA,
    const int* __restrict__ rpA, const int* __restrict__ srcA,
    const f16* __restrict__ hsA, OUT* __restrict__ outA, int nA,
    const float* __restrict__ elB, const float* __restrict__ erB,
    const int* __restrict__ rpB, const int* __restrict__ srcB,
    const f16* __restrict__ hsB, OUT* __restrict__ outB, int nB) {
  constexpr int CPL = W >> 6;   // channels per lane
  constexpr bool OF16 = (sizeof(OUT) == 2);
  __shared__ float alds[4][256];   // [wave][edge*4 + head]
  int wv = threadIdx.x >> 6;
  int g = blockIdx.x * 4 + wv;
  int lane = threadIdx.x & 63;
  const float* el; const float* er; const int* rp; const int* srcv;
  const f16* hs; OUT* outp; int d;
  if (g < nA)           { el = elA; er = erA; rp = rpA; srcv = srcA; hs = hsA; outp = outA; d = g; }
  else if (g < nA + nB) { el = elB; er = erB; rp = rpB; srcv = srcB; hs = hsB; outp = outB; d = g - nA; }
  else return;
  int s0 = rp[d], s1 = rp[d + 1];
  int deg = s1 - s0;
  int c0 = lane * CPL;
  int h = c0 / DH;
  long obase = (long)d * W + c0;
  if (deg == 0) {
#pragma unroll
    for (int q = 0; q < CPL; ++q) outp[obase + q] = (OUT)0.f;
    return;
  }
  float4 er4 = *(const float4*)&er[d * 4];
  const float NEG = -3.0e38f;
  float acc[CPL];
#pragma unroll
  for (int q = 0; q < CPL; ++q) acc[q] = 0.f;
  float inv;

  if (deg <= 64) {
    int k = s0 + lane;
    int sreg = 0;
    float v0 = NEG, v1 = NEG, v2 = NEG, v3 = NEG;
    if (k < s1) {
      sreg = srcv[k];
      float4 e4 = *(const float4*)&el[sreg * 4];
      v0 = e4.x + er4.x; v0 = v0 > 0.f ? v0 : 0.2f * v0;
      v1 = e4.y + er4.y; v1 = v1 > 0.f ? v1 : 0.2f * v1;
      v2 = e4.z + er4.z; v2 = v2 > 0.f ? v2 : 0.2f * v2;
      v3 = e4.w + er4.w; v3 = v3 > 0.f ? v3 : 0.2f * v3;
    }
    float m0 = v0, m1 = v1, m2 = v2, m3 = v3;
#pragma unroll
    for (int off = 32; off; off >>= 1) {
      m0 = fmaxf(m0, __shfl_xor(m0, off, 64));
      m1 = fmaxf(m1, __shfl_xor(m1, off, 64));
      m2 = fmaxf(m2, __shfl_xor(m2, off, 64));
      m3 = fmaxf(m3, __shfl_xor(m3, off, 64));
    }
    float e0 = 0.f, e1 = 0.f, e2 = 0.f, e3 = 0.f;
    if (k < s1) {
      e0 = expf(v0 - m0); e1 = expf(v1 - m1);
      e2 = expf(v2 - m2); e3 = expf(v3 - m3);
    }
    *(float4*)&alds[wv][lane * 4] = make_float4(e0, e1, e2, e3);
    float S0 = e0, S1 = e1, S2 = e2, S3 = e3;
#pragma unroll
    for (int off = 32; off; off >>= 1) {
      S0 += __shfl_xor(S0, off, 64);
      S1 += __shfl_xor(S1, off, 64);
      S2 += __shfl_xor(S2, off, 64);
      S3 += __shfl_xor(S3, off, 64);
    }
    float Sh = h == 0 ? S0 : h == 1 ? S1 : h == 2 ? S2 : S3;
    inv = 1.0f / Sh;
    for (int j = 0; j < deg; ++j) {
      float aj = alds[wv][j * 4 + h];
      int sj = __shfl(sreg, j, 64);
      const f16* row = &hs[(long)sj * W + c0];
      if constexpr (CPL == 4) {
        f16x4 hv = *(const f16x4*)row;
        acc[0] += aj * (float)hv[0]; acc[1] += aj * (float)hv[1];
        acc[2] += aj * (float)hv[2]; acc[3] += aj * (float)hv[3];
      } else {
        f16x2 hv = *(const f16x2*)row;
        acc[0] += aj * (float)hv[0]; acc[1] += aj * (float)hv[1];
      }
    }
  } else {
    float m0 = NEG, m1 = NEG, m2 = NEG, m3 = NEG;
    for (int k = s0 + lane; k < s1; k += 64) {
      int s = srcv[k];
      float4 e4 = *(const float4*)&el[s * 4];
      float v;
      v = e4.x + er4.x; v = v > 0.f ? v : 0.2f * v; m0 = fmaxf(m0, v);
      v = e4.y + er4.y; v = v > 0.f ? v : 0.2f * v; m1 = fmaxf(m1, v);
      v = e4.z + er4.z; v = v > 0.f ? v : 0.2f * v; m2 = fmaxf(m2, v);
      v = e4.w + er4.w; v = v > 0.f ? v : 0.2f * v; m3 = fmaxf(m3, v);
    }
#pragma unroll
    for (int off = 32; off; off >>= 1) {
      m0 = fmaxf(m0, __shfl_xor(m0, off, 64));
      m1 = fmaxf(m1, __shfl_xor(m1, off, 64));
      m2 = fmaxf(m2, __shfl_xor(m2, off, 64));
      m3 = fmaxf(m3, __shfl_xor(m3, off, 64));
    }
    float S0 = 0.f, S1 = 0.f, S2 = 0.f, S3 = 0.f;
    for (int k = s0 + lane; k < s1; k += 64) {
      int s = srcv[k];
      float4 e4 = *(const float4*)&el[s * 4];
      float v;
      v = e4.x + er4.x; v = v > 0.f ? v : 0.2f * v; S0 += expf(v - m0);
      v = e4.y + er4.y; v = v > 0.f ? v : 0.2f * v; S1 += expf(v - m1);
      v = e4.z + er4.z; v = v > 0.f ? v : 0.2f * v; S2 += expf(v - m2);
      v = e4.w + er4.w; v = v > 0.f ? v : 0.2f * v; S3 += expf(v - m3);
    }
#pragma unroll
    for (int off = 32; off; off >>= 1) {
      S0 += __shfl_xor(S0, off, 64);
      S1 += __shfl_xor(S1, off, 64);
      S2 += __shfl_xor(S2, off, 64);
      S3 += __shfl_xor(S3, off, 64);
    }
    float mh = h == 0 ? m0 : h == 1 ? m1 : h == 2 ? m2 : m3;
    float Sh = h == 0 ? S0 : h == 1 ? S1 : h == 2 ? S2 : S3;
    float erh = h == 0 ? er4.x : h == 1 ? er4.y : h == 2 ? er4.z : er4.w;
    inv = 1.0f / Sh;
    for (int k = s0; k < s1; ++k) {
      int s = srcv[k];
      float v = el[s * 4 + h] + erh; v = v > 0.f ? v : 0.2f * v;
      float a = expf(v - mh);
      const f16* row = &hs[(long)s * W + c0];
      if constexpr (CPL == 4) {
        f16x4 hv = *(const f16x4*)row;
        acc[0] += a * (float)hv[0]; acc[1] += a * (float)hv[1];
        acc[2] += a * (float)hv[2]; acc[3] += a * (float)hv[3];
      } else {
        f16x2 hv = *(const f16x2*)row;
        acc[0] += a * (float)hv[0]; acc[1] += a * (float)hv[1];
      }
    }
  }
  if constexpr (OF16) {
    if constexpr (CPL == 4) {
      f16x4 o = { (f16)(acc[0] * inv), (f16)(acc[1] * inv), (f16)(acc[2] * inv), (f16)(acc[3] * inv) };
      *(f16x4*)&outp[obase] = o;
    } else {
      f16x2 o = { (f16)(acc[0] * inv), (f16)(acc[1] * inv) };
      *(f16x2*)&outp[obase] = o;
    }
  } else {
    if constexpr (CPL == 4) {
      *(float4*)&outp[obase] = make_float4(acc[0] * inv, acc[1] * inv, acc[2] * inv, acc[3] * inv);
    } else {
      *(float2*)&outp[obase] = make_float2(acc[0] * inv, acc[1] * inv);
    }
  }
}

// ---------- BN zero ----------
__global__ void zero2_k(float* __restrict__ a, float* __restrict__ b) {
  int t = threadIdx.x;
  a[t] = 0.f; b[t] = 0.f;
}

// ---------- BN stats (f16 input), both sides ----------
__global__ __launch_bounds__(256) void bn_stats2_k(const f16* __restrict__ xu, float* __restrict__ su, int Nu, int gU,
                                                   const f16* __restrict__ xi, float* __restrict__ si, int Ni) {
  const int C = 256;
  int b = blockIdx.x;
  const f16* x; float* sums; int N; int r0;
  if (b < gU) { x = xu; sums = su; N = Nu; r0 = b * 64; }
  else        { x = xi; sums = si; N = Ni; r0 = (b - gU) * 64; }
  int c = threadIdx.x;
  int r1 = min(r0 + 64, N);
  float s = 0.f, s2 = 0.f;
  for (int r = r0; r < r1; ++r) {
    float v = (float)x[(long)r * C + c];
    s += v; s2 += v * v;
  }
  atomicAdd(&sums[c], s);
  atomicAdd(&sums[C + c], s2);
}

// ---------- fused BN apply + activation -> f16 AND next-layer el/er; block per row ----------
__global__ __launch_bounds__(256) void bn_fused_k(
    const f16* __restrict__ xu, const float* __restrict__ su, const float* __restrict__ gbu,
    f16* __restrict__ yu, int Nu,
    const f16* __restrict__ xi, const float* __restrict__ si, const float* __restrict__ gbi,
    f16* __restrict__ yi, int Ni,
    const float* __restrict__ efu, const float* __restrict__ efiu,   // next-layer folds, K=256
    float* __restrict__ el_u, float* __restrict__ er_u,
    float* __restrict__ el_i, float* __restrict__ er_i, int act) {
  const int Kn = 256;
  __shared__ float xs[256];
  int b = blockIdx.x, t = threadIdx.x;
  const f16* x; const float* sums; const float* gb; f16* y; int n; int N;
  const float* elf; const float* erf; float* el; float* er;
  if (b < Nu) { x = xu; sums = su; gb = gbu; y = yu; n = b; N = Nu; elf = efu;  erf = efiu + 4 * Kn; el = el_u; er = er_u; }
  else        { x = xi; sums = si; gb = gbi; y = yi; n = b - Nu; N = Ni; elf = efiu; erf = efu + 4 * Kn;  el = el_i; er = er_i; }
  long base = (long)n * 256;
  float val = (float)x[base + t];
  float inv_n = 1.0f / (float)N;
  float mean = sums[t] * inv_n;
  float var = sums[256 + t] * inv_n - mean * mean;
  float v = gb[t] * (val - mean) * rsqrtf(var + 1e-5f) + gb[256 + t];
  v = act ? tanhf(v) : (v > 0.f ? v : 0.01f * v);
  y[base + t] = (f16)v;
  xs[t] = v;
  __syncthreads();
  int j = t >> 5, l = t & 31;
  const float* fr = (j < 4) ? (elf + j * Kn) : (erf + (j - 4) * Kn);
  float p = 0.f;
  for (int f = l; f < Kn; f += 32) p += xs[f] * fr[f];
#pragma unroll
  for (int off = 16; off; off >>= 1) p += __shfl_down(p, off, 32);
  if (l == 0) { if (j < 4) el[n * 4 + j] = p; else er[n * 4 + (j - 4)] = p; }
}

extern "C" void kernel_launch(void* const* d_in, const int* in_sizes, int n_in,
                              void* d_out, int out_size, void* d_ws, size_t ws_size,
                              hipStream_t stream) {
  const float* x_user = (const float*)d_in[0];
  const float* x_item = (const float*)d_in[1];
  const int* eu = (const int*)d_in[2];
  const int* ei = (const int*)d_in[3];
  const float *Wm[4][2], *Am[4][2];
  for (int L = 0; L < 4; ++L) {
    Wm[L][0] = (const float*)d_in[4 + L * 4 + 0];
    Am[L][0] = (const float*)d_in[4 + L * 4 + 1];
    Wm[L][1] = (const float*)d_in[4 + L * 4 + 2];
    Am[L][1] = (const float*)d_in[4 + L * 4 + 3];
  }
  const float* bnu = (const float*)d_in[20];
  const float* bni = (const float*)d_in[21];
  float* out = (float*)d_out;

  float* ws = (float*)d_ws;
  size_t o = 0;
  float* el_u = ws + o; o += (size_t)NUSERS * 4;
  float* er_u = ws + o; o += (size_t)NUSERS * 4;
  float* el_i = ws + o; o += (size_t)NITEMS * 4;
  float* er_i = ws + o; o += (size_t)NITEMS * 4;
  float* ef_all[4][2];
  for (int L = 0; L < 4; ++L)
    for (int rl = 0; rl < 2; ++rl) { ef_all[L][rl] = ws + o; o += 2048; }
  float* bns_u = ws + o; o += 512;
  float* bns_i = ws + o; o += 512;
  // f16 buffers (offsets in float units; all 16B aligned)
  f16* hb_u   = (f16*)(ws + o); o += (size_t)NUSERS * 128;
  f16* hb_i   = (f16*)(ws + o); o += (size_t)NITEMS * 128;
  f16* hsb_u  = (f16*)(ws + o); o += (size_t)NUSERS * 128;
  f16* hsb_i  = (f16*)(ws + o); o += (size_t)NITEMS * 128;
  f16* aggh_u = (f16*)(ws + o); o += (size_t)NUSERS * 128;
  f16* aggh_i = (f16*)(ws + o); o += (size_t)NITEMS * 128;
  f16* Bt_all[4][2];
  for (int L = 0; L < 4; ++L) {
    int K = (L == 0) ? 128 : 256;
    int W = (L == 3) ? 128 : 256;
    for (int rl = 0; rl < 2; ++rl) { Bt_all[L][rl] = (f16*)(ws + o); o += (size_t)K * W / 2; }
  }
  // CSR scratch (deg_i/deg_u adjacent => single memset)
  int* deg_i    = (int*)(ws + o); o += NITEMS;
  int* deg_u    = (int*)(ws + o); o += NUSERS;
  int* rowptr_i = (int*)(ws + o); o += NITEMS + 1;
  int* rowptr_u = (int*)(ws + o); o += NUSERS + 1;
  int* cur_i    = (int*)(ws + o); o += NITEMS;
  int* cur_u    = (int*)(ws + o); o += NUSERS;
  int* bsum     = (int*)(ws + o); o += 256;
  int* csrsrc_i = (int*)(ws + o); o += NEDGES;
  int* csrsrc_u = (int*)(ws + o); o += NEDGES;

  const int gE2 = (2 * NEDGES + 255) / 256;
  const int nb_i = (NITEMS + 1023) / 1024;
  const int nb_u = (NUSERS + 1023) / 1024;
  const int gU = (NUSERS + 63) / 64;
  const int gI = (NITEMS + 63) / 64;

  // ---- CSR build (once; edges identical across layers) ----
  hipMemsetAsync(deg_i, 0, (NITEMS + NUSERS) * sizeof(int), stream);
  hist_k<<<dim3(gE2), dim3(256), 0, stream>>>(ei, deg_i, eu, deg_u);
  scan1_k<<<dim3(nb_i), dim3(256), 0, stream>>>(deg_i, bsum, NITEMS);
  scan2_k<<<dim3(1), dim3(64), 0, stream>>>(bsum, nb_i);
  scan3_k<<<dim3(nb_i), dim3(256), 0, stream>>>(deg_i, bsum, rowptr_i, NITEMS);
  setval_k<<<dim3(1), dim3(1), 0, stream>>>(rowptr_i + NITEMS, NEDGES);
  scan1_k<<<dim3(nb_u), dim3(256), 0, stream>>>(deg_u, bsum, NUSERS);
  scan2_k<<<dim3(1), dim3(64), 0, stream>>>(bsum, nb_u);
  scan3_k<<<dim3(nb_u), dim3(256), 0, stream>>>(deg_u, bsum, rowptr_u, NUSERS);
  setval_k<<<dim3(1), dim3(1), 0, stream>>>(rowptr_u + NUSERS, NEDGES);
  copy2_k<<<dim3((NITEMS + NUSERS + 255) / 256), dim3(256), 0, stream>>>(rowptr_i, cur_i, NITEMS, rowptr_u, cur_u, NUSERS);
  scat_k<<<dim3(gE2), dim3(256), 0, stream>>>(ei, eu, cur_i, csrsrc_i, cur_u, csrsrc_u);

  // ---- all layer preps upfront (Bt + el/er folds) ----
  for (int L = 0; L < 4; ++L) {
    int K = (L == 0) ? 128 : 256;
    int dh = (L == 3) ? 32 : 64;
    int W = 4 * dh;
    prep_k<<<dim3((2 * K * W + 255) / 256), dim3(256), 0, stream>>>(
        Wm[L][0], Am[L][0], Bt_all[L][0], ef_all[L][0],
        Wm[L][1], Am[L][1], Bt_all[L][1], ef_all[L][1], K, W, dh);
  }

  // layer-0 inputs -> f16; layer-0 el/er
  xcvt_k<<<dim3(((NUSERS + NITEMS) * 128 + 255) / 256), dim3(256), 0, stream>>>(
      x_user, hb_u, (long)NUSERS * 128, x_item, hb_i, (long)NITEMS * 128);
  eler_k<<<dim3(NUSERS + NITEMS), dim3(256), 0, stream>>>(
      hb_u, ef_all[0][0], ef_all[0][1], el_u, er_u, hb_i, el_i, er_i, 128);

  int K = 128;
  for (int L = 0; L < 4; ++L) {
    const int dh = (L == 3) ? 32 : 64;
    const int W = 4 * dh;

    const int gya = (NUSERS + 127) / 128, gyb = (NITEMS + 127) / 128;
    hgemm2_k<<<dim3(W / 128, gya + gyb), dim3(256), 0, stream>>>(
        hb_u, Bt_all[L][0], hsb_u, NUSERS, gya, hb_i, Bt_all[L][1], hsb_i, NITEMS, W, K);

    const int gAgg = (NITEMS + NUSERS + 3) / 4;
    if (L < 3) {
      agg_k<256, 64, f16><<<dim3(gAgg), dim3(256), 0, stream>>>(
          el_u, er_i, rowptr_i, csrsrc_i, hsb_u, aggh_i, NITEMS,
          el_i, er_u, rowptr_u, csrsrc_u, hsb_i, aggh_u, NUSERS);
      zero2_k<<<dim3(1), dim3(512), 0, stream>>>(bns_u, bns_i);
      bn_stats2_k<<<dim3(gU + gI), dim3(256), 0, stream>>>(aggh_u, bns_u, NUSERS, gU, aggh_i, bns_i, NITEMS);
      // BN apply + activation -> hb, AND el/er for layer L+1 (folds of L+1, K=256)
      bn_fused_k<<<dim3(NUSERS + NITEMS), dim3(256), 0, stream>>>(
          aggh_u, bns_u, bnu + L * 512, hb_u, NUSERS,
          aggh_i, bns_i, bni + L * 512, hb_i, NITEMS,
          ef_all[L + 1][0], ef_all[L + 1][1],
          el_u, er_u, el_i, er_i, L == 2);
      K = 256;
    } else {
      agg_k<128, 32, float><<<dim3(gAgg), dim3(256), 0, stream>>>(
          el_u, er_i, rowptr_i, csrsrc_i, hsb_u, out + (size_t)NUSERS * 128, NITEMS,
          el_i, er_u, rowptr_u, csrsrc_u, hsb_i, out, NUSERS);
    }
  }
}

// Round 8
// 917.557 us; speedup vs baseline: 4.5069x; 1.0861x over previous
//
#include <hip/hip_runtime.h>

#define NUSERS 50000
#define NITEMS 20000
#define NEDGES 400000

typedef _Float16 f16;
typedef __attribute__((ext_vector_type(8))) _Float16 f16x8;
typedef __attribute__((ext_vector_type(4))) _Float16 f16x4;
typedef __attribute__((ext_vector_type(2))) _Float16 f16x2;
typedef __attribute__((ext_vector_type(4))) float f32x4;

// ---------- prep: weight transpose->f16 + folded el/er projections, both relations ----------
__global__ void prep_k(const float* __restrict__ Wa, const float* __restrict__ Aa,
                       f16* __restrict__ Bta, float* __restrict__ efa,
                       const float* __restrict__ Wb, const float* __restrict__ Ab,
                       f16* __restrict__ Btb, float* __restrict__ efb,
                       int K, int Nw, int dh) {
  int t = blockIdx.x * blockDim.x + threadIdx.x;
  int half = K * Nw;
  if (t >= 2 * half) return;
  const float* W = (t < half) ? Wa : Wb;
  const float* A = (t < half) ? Aa : Ab;
  f16* Bt = (t < half) ? Bta : Btb;
  float* ef = (t < half) ? efa : efb;
  int t2 = (t < half) ? t : t - half;
  int n = t2 / K, k = t2 - n * K;
  Bt[t2] = (f16)W[(long)k * Nw + n];
  if (t2 < K * 8) {
    int j = t2 / (K * 4);
    int r = t2 - j * K * 4;
    int h = r / K, f = r - h * K;
    const float* Aj = A + j * Nw;   // A[j], shape [4,dh], Nw = 4*dh
    float s = 0.f;
    for (int d = 0; d < dh; ++d) s += W[f * Nw + h * dh + d] * Aj[h * dh + d];
    ef[j * 4 * K + h * K + f] = s;
  }
}

// ---------- fp32 -> f16 convert, both sides in one launch ----------
__global__ void xcvt_k(const float* __restrict__ xu, f16* __restrict__ yu, long nu,
                       const float* __restrict__ xi, f16* __restrict__ yi, long ni) {
  long i = (long)blockIdx.x * blockDim.x + threadIdx.x;
  if (i < nu) yu[i] = (f16)xu[i];
  else if (i < nu + ni) yi[i - nu] = (f16)xi[i - nu];
}

// ---------- f16 MFMA GEMM, user+item fused: C = A[M,K] @ Bt[N,K]^T ----------
__global__ __launch_bounds__(256) void hgemm2_k(const f16* __restrict__ Aa, const f16* __restrict__ Bta,
                                                f16* __restrict__ Ca, int Ma, int gya,
                                                const f16* __restrict__ Ab, const f16* __restrict__ Btb,
                                                f16* __restrict__ Cb, int Mb,
                                                int N, int K) {
  __shared__ f16 As[128 * 32];
  __shared__ f16 Bs[128 * 32];
  int by = blockIdx.y;
  const f16* A; const f16* Bt; f16* C; int M; int row0;
  if (by < gya) { A = Aa; Bt = Bta; C = Ca; M = Ma; row0 = by * 128; }
  else          { A = Ab; Bt = Btb; C = Cb; M = Mb; row0 = (by - gya) * 128; }
  int tid = threadIdx.x;
  int col0 = blockIdx.x * 128;
  int lane = tid & 63, wv = tid >> 6;
  int wr = (wv & 1) * 64, wc = (wv >> 1) * 64;
  int l16 = lane & 15, q = lane >> 4;
  f32x4 acc[4][4] = {};
  int r = tid >> 2, c8 = (tid & 3) * 8;
  for (int k0 = 0; k0 < K; k0 += 32) {
    int ra = min(row0 + r, M - 1);
    uint4 va = *(const uint4*)&A[(long)ra * K + k0 + c8];
    int ra2 = min(row0 + r + 64, M - 1);
    uint4 va2 = *(const uint4*)&A[(long)ra2 * K + k0 + c8];
    uint4 vb = *(const uint4*)&Bt[(long)(col0 + r) * K + k0 + c8];
    uint4 vb2 = *(const uint4*)&Bt[(long)(col0 + r + 64) * K + k0 + c8];
    *(uint4*)&As[r * 32 + c8] = va;
    *(uint4*)&As[(r + 64) * 32 + c8] = va2;
    *(uint4*)&Bs[r * 32 + c8] = vb;
    *(uint4*)&Bs[(r + 64) * 32 + c8] = vb2;
    __syncthreads();
    f16x8 af[4], bfr[4];
#pragma unroll
    for (int i = 0; i < 4; ++i) {
      af[i] = *(const f16x8*)&As[(wr + i * 16 + l16) * 32 + q * 8];
      bfr[i] = *(const f16x8*)&Bs[(wc + i * 16 + l16) * 32 + q * 8];
    }
#pragma unroll
    for (int i = 0; i < 4; ++i)
#pragma unroll
      for (int j = 0; j < 4; ++j)
        acc[i][j] = __builtin_amdgcn_mfma_f32_16x16x32_f16(af[i], bfr[j], acc[i][j], 0, 0, 0);
    __syncthreads();
  }
#pragma unroll
  for (int i = 0; i < 4; ++i) {
#pragma unroll
    for (int reg = 0; reg < 4; ++reg) {
      int rr = row0 + wr + i * 16 + q * 4 + reg;
      if (rr < M) {
#pragma unroll
        for (int j = 0; j < 4; ++j)
          C[(long)rr * N + col0 + wc + j * 16 + l16] = (f16)acc[i][j][reg];
      }
    }
  }
}

// ---------- el+er via folds (layer 0 only); block per node ----------
__global__ __launch_bounds__(256) void eler_k(
    const f16* __restrict__ hbu, const float* __restrict__ ef_ui, const float* __restrict__ ef_iu,
    float* __restrict__ el_u, float* __restrict__ er_u,
    const f16* __restrict__ hbi, float* __restrict__ el_i, float* __restrict__ er_i, int K) {
  __shared__ float xs[256];
  int b = blockIdx.x, t = threadIdx.x;
  const f16* hb; const float* elf; const float* erf; float* el; float* er; int n;
  if (b < NUSERS) { hb = hbu; elf = ef_ui; erf = ef_iu + 4 * K; el = el_u; er = er_u; n = b; }
  else            { hb = hbi; elf = ef_iu; erf = ef_ui + 4 * K; el = el_i; er = er_i; n = b - NUSERS; }
  if (t < K) xs[t] = (float)hb[(long)n * K + t];
  __syncthreads();
  int j = t >> 5, l = t & 31;
  const float* fr = (j < 4) ? (elf + j * K) : (erf + (j - 4) * K);
  float p = 0.f;
  for (int f = l; f < K; f += 32) p += xs[f] * fr[f];
#pragma unroll
  for (int off = 16; off; off >>= 1) p += __shfl_down(p, off, 32);
  if (l == 0) { if (j < 4) el[n * 4 + j] = p; else er[n * 4 + (j - 4)] = p; }
}

// ---------- CSR build ----------
__global__ void hist_k(const int* __restrict__ ei, int* __restrict__ degi,
                       const int* __restrict__ eu, int* __restrict__ degu) {
  int e = blockIdx.x * blockDim.x + threadIdx.x;
  if (e < NEDGES) atomicAdd(&degi[ei[e]], 1);
  else if (e < 2 * NEDGES) atomicAdd(&degu[eu[e - NEDGES]], 1);
}

__global__ __launch_bounds__(256) void scan1_k(const int* __restrict__ deg,
                                               int* __restrict__ bsum, int N) {
  __shared__ int red[256];
  int base = blockIdx.x * 1024, t = threadIdx.x;
  int s = 0;
#pragma unroll
  for (int j = 0; j < 4; ++j) { int i = base + t * 4 + j; s += (i < N) ? deg[i] : 0; }
  red[t] = s; __syncthreads();
  for (int off = 128; off; off >>= 1) { if (t < off) red[t] += red[t + off]; __syncthreads(); }
  if (t == 0) bsum[blockIdx.x] = red[0];
}

__global__ void scan2_k(int* __restrict__ bsum, int nb) {
  if (threadIdx.x == 0) {
    int run = 0;
    for (int i = 0; i < nb; ++i) { int v = bsum[i]; bsum[i] = run; run += v; }
  }
}

__global__ __launch_bounds__(256) void scan3_k(const int* __restrict__ deg,
                                               const int* __restrict__ bsum,
                                               int* __restrict__ rowptr, int N) {
  __shared__ int tsum[256];
  int base = blockIdx.x * 1024, t = threadIdx.x;
  int v[4]; int s = 0;
#pragma unroll
  for (int j = 0; j < 4; ++j) { int i = base + t * 4 + j; v[j] = (i < N) ? deg[i] : 0; s += v[j]; }
  tsum[t] = s; __syncthreads();
  for (int off = 1; off < 256; off <<= 1) {
    int x = (t >= off) ? tsum[t - off] : 0;
    __syncthreads();
    tsum[t] += x;
    __syncthreads();
  }
  int run = bsum[blockIdx.x] + ((t > 0) ? tsum[t - 1] : 0);
#pragma unroll
  for (int j = 0; j < 4; ++j) {
    int i = base + t * 4 + j;
    if (i < N) rowptr[i] = run;
    run += v[j];
  }
}

__global__ void setval_k(int* __restrict__ p, int v) { *p = v; }

__global__ void copy2_k(const int* __restrict__ a, int* __restrict__ b, int Na,
                        const int* __restrict__ c, int* __restrict__ d, int Nc) {
  int i = blockIdx.x * blockDim.x + threadIdx.x;
  if (i < Na) b[i] = a[i];
  else if (i < Na + Nc) d[i - Na] = c[i - Na];
}

__global__ void scat_k(const int* __restrict__ ei, const int* __restrict__ eu,
                       int* __restrict__ curi, int* __restrict__ srci,
                       int* __restrict__ curu, int* __restrict__ srcu) {
  int e = blockIdx.x * blockDim.x + threadIdx.x;
  if (e < NEDGES) {
    int p = atomicAdd(&curi[ei[e]], 1);
    srci[p] = eu[e];
  } else if (e < 2 * NEDGES) {
    int e2 = e - NEDGES;
    int p = atomicAdd(&curu[eu[e2]], 1);
    srcu[p] = ei[e2];
  }
}

// ---------- fused segment-softmax + gather; wave per dst ----------
// Softmax lane map: lane = (edge slot p = lane>>2, head hh = lane&3); segmented
// butterfly (xor 4,8,16,32) reduces over slots within each head. Exp staged to
// LDS [slot*4+head]; precomputed row byte-offsets staged beside. Gather reads
// its OWN channel-head h = c0/DH.
template <int W, int DH, typename OUT>
__global__ __launch_bounds__(256) void agg_k(
    const float* __restrict__ elA, const float* __restrict__ erA,
    const int* __restrict__ rpA, const int* __restrict__ srcA,
    const f16* __restrict__ hsA, OUT* __restrict__ outA, int nA,
    const float* __restrict__ elB, const float* __restrict__ erB,
    const int* __restrict__ rpB, const int* __restrict__ srcB,
    const f16* __restrict__ hsB, OUT* __restrict__ outB, int nB) {
  constexpr int CPL = W >> 6;                   // channels per lane
  constexpr int SHIFT = (W == 256) ? 9 : 8;     // log2(W * sizeof(f16))
  constexpr bool OF16 = (sizeof(OUT) == 2);
  __shared__ float alds[4][256];   // [wave][slot*4 + head]
  __shared__ int soff[4][64];      // [wave][slot] = src row byte offset
  int wv = threadIdx.x >> 6;
  int g = blockIdx.x * 4 + wv;
  int lane = threadIdx.x & 63;
  const float* el; const float* er; const int* rp; const int* srcv;
  const f16* hs; OUT* outp; int d;
  if (g < nA)           { el = elA; er = erA; rp = rpA; srcv = srcA; hs = hsA; outp = outA; d = g; }
  else if (g < nA + nB) { el = elB; er = erB; rp = rpB; srcv = srcB; hs = hsB; outp = outB; d = g - nA; }
  else return;
  int s0 = rp[d], s1 = rp[d + 1];
  int deg = s1 - s0;
  int c0 = lane * CPL;
  int h = c0 / DH;
  long obase = (long)d * W + c0;
  if (deg == 0) {
#pragma unroll
    for (int q = 0; q < CPL; ++q) outp[obase + q] = (OUT)0.f;
    return;
  }
  const float NEG = -3.0e38f;
  float acc[CPL];
#pragma unroll
  for (int q = 0; q < CPL; ++q) acc[q] = 0.f;
  float inv;

  if (deg <= 64) {
    int hh = lane & 3, p = lane >> 2;
    float er_h = er[d * 4 + hh];
    float vv[4];
    float vmax = NEG;
#pragma unroll
    for (int j = 0; j < 4; ++j) {
      int slot = j * 16 + p;
      vv[j] = NEG;
      if (slot < deg) {
        int sj = srcv[s0 + slot];
        if (hh == 0) soff[wv][slot] = sj << SHIFT;
        float v = el[sj * 4 + hh] + er_h;
        v = v > 0.f ? v : 0.2f * v;
        vv[j] = v;
        vmax = fmaxf(vmax, v);
      }
    }
#pragma unroll
    for (int off = 4; off < 64; off <<= 1) vmax = fmaxf(vmax, __shfl_xor(vmax, off, 64));
    float ssum = 0.f;
#pragma unroll
    for (int j = 0; j < 4; ++j) {
      int slot = j * 16 + p;
      if (slot < deg) {
        float e = expf(vv[j] - vmax);
        alds[wv][slot * 4 + hh] = e;
        ssum += e;
      }
    }
#pragma unroll
    for (int off = 4; off < 64; off <<= 1) ssum += __shfl_xor(ssum, off, 64);
    float Sh = __shfl(ssum, (lane & ~3) | h, 64);
    inv = 1.0f / Sh;
    const char* hbase = (const char*)hs + (size_t)c0 * sizeof(f16);
    for (int j = 0; j < deg; ++j) {
      float aj = alds[wv][j * 4 + h];
      int off = soff[wv][j];
      const f16* row = (const f16*)(hbase + (size_t)(unsigned)off);
      if constexpr (CPL == 4) {
        f16x4 hv = *(const f16x4*)row;
        acc[0] += aj * (float)hv[0]; acc[1] += aj * (float)hv[1];
        acc[2] += aj * (float)hv[2]; acc[3] += aj * (float)hv[3];
      } else {
        f16x2 hv = *(const f16x2*)row;
        acc[0] += aj * (float)hv[0]; acc[1] += aj * (float)hv[1];
      }
    }
  } else {
    // ---- generic fallback (deg > 64): strided two-pass + serial gather ----
    float4 er4 = *(const float4*)&er[d * 4];
    float m0 = NEG, m1 = NEG, m2 = NEG, m3 = NEG;
    for (int k = s0 + lane; k < s1; k += 64) {
      int s = srcv[k];
      float4 e4 = *(const float4*)&el[s * 4];
      float v;
      v = e4.x + er4.x; v = v > 0.f ? v : 0.2f * v; m0 = fmaxf(m0, v);
      v = e4.y + er4.y; v = v > 0.f ? v : 0.2f * v; m1 = fmaxf(m1, v);
      v = e4.z + er4.z; v = v > 0.f ? v : 0.2f * v; m2 = fmaxf(m2, v);
      v = e4.w + er4.w; v = v > 0.f ? v : 0.2f * v; m3 = fmaxf(m3, v);
    }
#pragma unroll
    for (int off = 32; off; off >>= 1) {
      m0 = fmaxf(m0, __shfl_xor(m0, off, 64));
      m1 = fmaxf(m1, __shfl_xor(m1, off, 64));
      m2 = fmaxf(m2, __shfl_xor(m2, off, 64));
      m3 = fmaxf(m3, __shfl_xor(m3, off, 64));
    }
    float S0 = 0.f, S1 = 0.f, S2 = 0.f, S3 = 0.f;
    for (int k = s0 + lane; k < s1; k += 64) {
      int s = srcv[k];
      float4 e4 = *(const float4*)&el[s * 4];
      float v;
      v = e4.x + er4.x; v = v > 0.f ? v : 0.2f * v; S0 += expf(v - m0);
      v = e4.y + er4.y; v = v > 0.f ? v : 0.2f * v; S1 += expf(v - m1);
      v = e4.z + er4.z; v = v > 0.f ? v : 0.2f * v; S2 += expf(v - m2);
      v = e4.w + er4.w; v = v > 0.f ? v : 0.2f * v; S3 += expf(v - m3);
    }
#pragma unroll
    for (int off = 32; off; off >>= 1) {
      S0 += __shfl_xor(S0, off, 64);
      S1 += __shfl_xor(S1, off, 64);
      S2 += __shfl_xor(S2, off, 64);
      S3 += __shfl_xor(S3, off, 64);
    }
    float mh = h == 0 ? m0 : h == 1 ? m1 : h == 2 ? m2 : m3;
    float Sh = h == 0 ? S0 : h == 1 ? S1 : h == 2 ? S2 : S3;
    float erh = h == 0 ? er4.x : h == 1 ? er4.y : h == 2 ? er4.z : er4.w;
    inv = 1.0f / Sh;
    for (int k = s0; k < s1; ++k) {
      int s = srcv[k];
      float v = el[s * 4 + h] + erh; v = v > 0.f ? v : 0.2f * v;
      float a = expf(v - mh);
      const f16* row = &hs[(long)s * W + c0];
      if constexpr (CPL == 4) {
        f16x4 hv = *(const f16x4*)row;
        acc[0] += a * (float)hv[0]; acc[1] += a * (float)hv[1];
        acc[2] += a * (float)hv[2]; acc[3] += a * (float)hv[3];
      } else {
        f16x2 hv = *(const f16x2*)row;
        acc[0] += a * (float)hv[0]; acc[1] += a * (float)hv[1];
      }
    }
  }
  if constexpr (OF16) {
    if constexpr (CPL == 4) {
      f16x4 o = { (f16)(acc[0] * inv), (f16)(acc[1] * inv), (f16)(acc[2] * inv), (f16)(acc[3] * inv) };
      *(f16x4*)&outp[obase] = o;
    } else {
      f16x2 o = { (f16)(acc[0] * inv), (f16)(acc[1] * inv) };
      *(f16x2*)&outp[obase] = o;
    }
  } else {
    if constexpr (CPL == 4) {
      *(float4*)&outp[obase] = make_float4(acc[0] * inv, acc[1] * inv, acc[2] * inv, acc[3] * inv);
    } else {
      *(float2*)&outp[obase] = make_float2(acc[0] * inv, acc[1] * inv);
    }
  }
}

// ---------- BN zero ----------
__global__ void zero2_k(float* __restrict__ a, float* __restrict__ b) {
  int t = threadIdx.x;
  a[t] = 0.f; b[t] = 0.f;
}

// ---------- BN stats (f16 input), both sides ----------
__global__ __launch_bounds__(256) void bn_stats2_k(const f16* __restrict__ xu, float* __restrict__ su, int Nu, int gU,
                                                   const f16* __restrict__ xi, float* __restrict__ si, int Ni) {
  const int C = 256;
  int b = blockIdx.x;
  const f16* x; float* sums; int N; int r0;
  if (b < gU) { x = xu; sums = su; N = Nu; r0 = b * 64; }
  else        { x = xi; sums = si; N = Ni; r0 = (b - gU) * 64; }
  int c = threadIdx.x;
  int r1 = min(r0 + 64, N);
  float s = 0.f, s2 = 0.f;
  for (int r = r0; r < r1; ++r) {
    float v = (float)x[(long)r * C + c];
    s += v; s2 += v * v;
  }
  atomicAdd(&sums[c], s);
  atomicAdd(&sums[C + c], s2);
}

// ---------- fused BN apply + activation -> f16 AND next-layer el/er; block per row ----------
__global__ __launch_bounds__(256) void bn_fused_k(
    const f16* __restrict__ xu, const float* __restrict__ su, const float* __restrict__ gbu,
    f16* __restrict__ yu, int Nu,
    const f16* __restrict__ xi, const float* __restrict__ si, const float* __restrict__ gbi,
    f16* __restrict__ yi, int Ni,
    const float* __restrict__ efu, const float* __restrict__ efiu,   // next-layer folds, K=256
    float* __restrict__ el_u, float* __restrict__ er_u,
    float* __restrict__ el_i, float* __restrict__ er_i, int act) {
  const int Kn = 256;
  __shared__ float xs[256];
  int b = blockIdx.x, t = threadIdx.x;
  const f16* x; const float* sums; const float* gb; f16* y; int n; int N;
  const float* elf; const float* erf; float* el; float* er;
  if (b < Nu) { x = xu; sums = su; gb = gbu; y = yu; n = b; N = Nu; elf = efu;  erf = efiu + 4 * Kn; el = el_u; er = er_u; }
  else        { x = xi; sums = si; gb = gbi; y = yi; n = b - Nu; N = Ni; elf = efiu; erf = efu + 4 * Kn;  el = el_i; er = er_i; }
  long base = (long)n * 256;
  float val = (float)x[base + t];
  float inv_n = 1.0f / (float)N;
  float mean = sums[t] * inv_n;
  float var = sums[256 + t] * inv_n - mean * mean;
  float v = gb[t] * (val - mean) * rsqrtf(var + 1e-5f) + gb[256 + t];
  v = act ? tanhf(v) : (v > 0.f ? v : 0.01f * v);
  y[base + t] = (f16)v;
  xs[t] = v;
  __syncthreads();
  int j = t >> 5, l = t & 31;
  const float* fr = (j < 4) ? (elf + j * Kn) : (erf + (j - 4) * Kn);
  float p = 0.f;
  for (int f = l; f < Kn; f += 32) p += xs[f] * fr[f];
#pragma unroll
  for (int off = 16; off; off >>= 1) p += __shfl_down(p, off, 32);
  if (l == 0) { if (j < 4) el[n * 4 + j] = p; else er[n * 4 + (j - 4)] = p; }
}

extern "C" void kernel_launch(void* const* d_in, const int* in_sizes, int n_in,
                              void* d_out, int out_size, void* d_ws, size_t ws_size,
                              hipStream_t stream) {
  const float* x_user = (const float*)d_in[0];
  const float* x_item = (const float*)d_in[1];
  const int* eu = (const int*)d_in[2];
  const int* ei = (const int*)d_in[3];
  const float *Wm[4][2], *Am[4][2];
  for (int L = 0; L < 4; ++L) {
    Wm[L][0] = (const float*)d_in[4 + L * 4 + 0];
    Am[L][0] = (const float*)d_in[4 + L * 4 + 1];
    Wm[L][1] = (const float*)d_in[4 + L * 4 + 2];
    Am[L][1] = (const float*)d_in[4 + L * 4 + 3];
  }
  const float* bnu = (const float*)d_in[20];
  const float* bni = (const float*)d_in[21];
  float* out = (float*)d_out;

  float* ws = (float*)d_ws;
  size_t o = 0;
  float* el_u = ws + o; o += (size_t)NUSERS * 4;
  float* er_u = ws + o; o += (size_t)NUSERS * 4;
  float* el_i = ws + o; o += (size_t)NITEMS * 4;
  float* er_i = ws + o; o += (size_t)NITEMS * 4;
  float* ef_all[4][2];
  for (int L = 0; L < 4; ++L)
    for (int rl = 0; rl < 2; ++rl) { ef_all[L][rl] = ws + o; o += 2048; }
  float* bns_u = ws + o; o += 512;
  float* bns_i = ws + o; o += 512;
  // f16 buffers (offsets in float units; all 16B aligned)
  f16* hb_u   = (f16*)(ws + o); o += (size_t)NUSERS * 128;
  f16* hb_i   = (f16*)(ws + o); o += (size_t)NITEMS * 128;
  f16* hsb_u  = (f16*)(ws + o); o += (size_t)NUSERS * 128;
  f16* hsb_i  = (f16*)(ws + o); o += (size_t)NITEMS * 128;
  f16* aggh_u = (f16*)(ws + o); o += (size_t)NUSERS * 128;
  f16* aggh_i = (f16*)(ws + o); o += (size_t)NITEMS * 128;
  f16* Bt_all[4][2];
  for (int L = 0; L < 4; ++L) {
    int K = (L == 0) ? 128 : 256;
    int W = (L == 3) ? 128 : 256;
    for (int rl = 0; rl < 2; ++rl) { Bt_all[L][rl] = (f16*)(ws + o); o += (size_t)K * W / 2; }
  }
  // CSR scratch (deg_i/deg_u adjacent => single memset)
  int* deg_i    = (int*)(ws + o); o += NITEMS;
  int* deg_u    = (int*)(ws + o); o += NUSERS;
  int* rowptr_i = (int*)(ws + o); o += NITEMS + 1;
  int* rowptr_u = (int*)(ws + o); o += NUSERS + 1;
  int* cur_i    = (int*)(ws + o); o += NITEMS;
  int* cur_u    = (int*)(ws + o); o += NUSERS;
  int* bsum     = (int*)(ws + o); o += 256;
  int* csrsrc_i = (int*)(ws + o); o += NEDGES;
  int* csrsrc_u = (int*)(ws + o); o += NEDGES;

  const int gE2 = (2 * NEDGES + 255) / 256;
  const int nb_i = (NITEMS + 1023) / 1024;
  const int nb_u = (NUSERS + 1023) / 1024;
  const int gU = (NUSERS + 63) / 64;
  const int gI = (NITEMS + 63) / 64;

  // ---- CSR build (once; edges identical across layers) ----
  hipMemsetAsync(deg_i, 0, (NITEMS + NUSERS) * sizeof(int), stream);
  hist_k<<<dim3(gE2), dim3(256), 0, stream>>>(ei, deg_i, eu, deg_u);
  scan1_k<<<dim3(nb_i), dim3(256), 0, stream>>>(deg_i, bsum, NITEMS);
  scan2_k<<<dim3(1), dim3(64), 0, stream>>>(bsum, nb_i);
  scan3_k<<<dim3(nb_i), dim3(256), 0, stream>>>(deg_i, bsum, rowptr_i, NITEMS);
  setval_k<<<dim3(1), dim3(1), 0, stream>>>(rowptr_i + NITEMS, NEDGES);
  scan1_k<<<dim3(nb_u), dim3(256), 0, stream>>>(deg_u, bsum, NUSERS);
  scan2_k<<<dim3(1), dim3(64), 0, stream>>>(bsum, nb_u);
  scan3_k<<<dim3(nb_u), dim3(256), 0, stream>>>(deg_u, bsum, rowptr_u, NUSERS);
  setval_k<<<dim3(1), dim3(1), 0, stream>>>(rowptr_u + NUSERS, NEDGES);
  copy2_k<<<dim3((NITEMS + NUSERS + 255) / 256), dim3(256), 0, stream>>>(rowptr_i, cur_i, NITEMS, rowptr_u, cur_u, NUSERS);
  scat_k<<<dim3(gE2), dim3(256), 0, stream>>>(ei, eu, cur_i, csrsrc_i, cur_u, csrsrc_u);

  // ---- all layer preps upfront (Bt + el/er folds) ----
  for (int L = 0; L < 4; ++L) {
    int K = (L == 0) ? 128 : 256;
    int dh = (L == 3) ? 32 : 64;
    int W = 4 * dh;
    prep_k<<<dim3((2 * K * W + 255) / 256), dim3(256), 0, stream>>>(
        Wm[L][0], Am[L][0], Bt_all[L][0], ef_all[L][0],
        Wm[L][1], Am[L][1], Bt_all[L][1], ef_all[L][1], K, W, dh);
  }

  // layer-0 inputs -> f16; layer-0 el/er
  xcvt_k<<<dim3(((NUSERS + NITEMS) * 128 + 255) / 256), dim3(256), 0, stream>>>(
      x_user, hb_u, (long)NUSERS * 128, x_item, hb_i, (long)NITEMS * 128);
  eler_k<<<dim3(NUSERS + NITEMS), dim3(256), 0, stream>>>(
      hb_u, ef_all[0][0], ef_all[0][1], el_u, er_u, hb_i, el_i, er_i, 128);

  int K = 128;
  for (int L = 0; L < 4; ++L) {
    const int dh = (L == 3) ? 32 : 64;
    const int W = 4 * dh;

    const int gya = (NUSERS + 127) / 128, gyb = (NITEMS + 127) / 128;
    hgemm2_k<<<dim3(W / 128, gya + gyb), dim3(256), 0, stream>>>(
        hb_u, Bt_all[L][0], hsb_u, NUSERS, gya, hb_i, Bt_all[L][1], hsb_i, NITEMS, W, K);

    const int gAgg = (NITEMS + NUSERS + 3) / 4;
    if (L < 3) {
      agg_k<256, 64, f16><<<dim3(gAgg), dim3(256), 0, stream>>>(
          el_u, er_i, rowptr_i, csrsrc_i, hsb_u, aggh_i, NITEMS,
          el_i, er_u, rowptr_u, csrsrc_u, hsb_i, aggh_u, NUSERS);
      zero2_k<<<dim3(1), dim3(512), 0, stream>>>(bns_u, bns_i);
      bn_stats2_k<<<dim3(gU + gI), dim3(256), 0, stream>>>(aggh_u, bns_u, NUSERS, gU, aggh_i, bns_i, NITEMS);
      bn_fused_k<<<dim3(NUSERS + NITEMS), dim3(256), 0, stream>>>(
          aggh_u, bns_u, bnu + L * 512, hb_u, NUSERS,
          aggh_i, bns_i, bni + L * 512, hb_i, NITEMS,
          ef_all[L + 1][0], ef_all[L + 1][1],
          el_u, er_u, el_i, er_i, L == 2);
      K = 256;
    } else {
      agg_k<128, 32, float><<<dim3(gAgg), dim3(256), 0, stream>>>(
          el_u, er_i, rowptr_i, csrsrc_i, hsb_u, out + (size_t)NUSERS * 128, NITEMS,
          el_i, er_u, rowptr_u, csrsrc_u, hsb_i, out, NUSERS);
    }
  }
}